// Round 9
// baseline (852.908 us; speedup 1.0000x reference)
//
#include <hip/hip_runtime.h>
#include <math.h>

#define BB 32
#define TD 2048
#define TE 1024
#define DIM 256
#define INDIM 80

typedef __attribute__((ext_vector_type(8))) _Float16 f16x8;
typedef __attribute__((ext_vector_type(4))) float f32x4;

__device__ __forceinline__ float sigmoidf_(float x){ return 1.f/(1.f+__expf(-x)); }

// async 16B global->LDS copy (direct DMA, no VGPR round-trip)
__device__ __forceinline__ void cp16(const _Float16* g, _Float16* l){
  __builtin_amdgcn_global_load_lds(
      (const __attribute__((address_space(1))) unsigned int*)g,
      (__attribute__((address_space(3))) unsigned int*)l, 16, 0, 0);
}

// ------- merged weight prep: conv reorders + 2-term fp16 splits, one launch -------
// [0,655360)        : Wf0  w0(512,256,5) -> [o][tap*256+ic] fp16
// [655360,1310720)  : Wf1  same for w1
// [1310720,1376256) : Wqh/Wql 2-term split (256x256)
// [1376256,1400832) : Wlh/Wll padded split (256,80)->[256][96]
// [1400832,1421312) : Wph/Wpl split (80x256)
__global__ __launch_bounds__(256) void k_prep(
    const float* __restrict__ w0, const float* __restrict__ w1,
    const float* __restrict__ Wq, const float* __restrict__ Wl,
    const float* __restrict__ Wp,
    _Float16* __restrict__ Wf0, _Float16* __restrict__ Wf1,
    _Float16* __restrict__ Wqh, _Float16* __restrict__ Wql,
    _Float16* __restrict__ Wlh, _Float16* __restrict__ Wll,
    _Float16* __restrict__ Wph, _Float16* __restrict__ Wpl)
{
  int i = blockIdx.x*256 + threadIdx.x;
  if (i < 655360){
    int o = i / 1280, kk = i - o*1280;
    int tap = kk >> 8, ic = kk & 255;
    Wf0[i] = (_Float16)w0[(size_t)o*1280 + ic*5 + tap];
  } else if (i < 1310720){
    int j = i - 655360;
    int o = j / 1280, kk = j - o*1280;
    int tap = kk >> 8, ic = kk & 255;
    Wf1[j] = (_Float16)w1[(size_t)o*1280 + ic*5 + tap];
  } else if (i < 1376256){
    int j = i - 1310720;
    float f = Wq[j];
    _Float16 h = (_Float16)f;
    Wqh[j] = h; Wql[j] = (_Float16)(f - (float)h);
  } else if (i < 1400832){
    int j = i - 1376256;
    int d = j / 96, k = j - d*96;
    float f = (k < INDIM) ? Wl[d*INDIM + k] : 0.f;
    _Float16 h = (_Float16)f;
    Wlh[j] = h; Wll[j] = (_Float16)(f - (float)h);
  } else {
    int j = i - 1400832;
    float f = Wp[j];
    _Float16 h = (_Float16)f;
    Wph[j] = h; Wpl[j] = (_Float16)(f - (float)h);
  }
}

// ------- enc prep: Eh = fp16(enc) [b][s][d];  EVt = fp16(enc+emb) transposed [b][d][s] ---
__global__ __launch_bounds__(256) void k_eprep(const float* __restrict__ enc,
    const float* __restrict__ emb, _Float16* __restrict__ Eh,
    _Float16* __restrict__ EVt)
{
  __shared__ float ls[64][65];
  int blk = blockIdx.x;                  // 32 b * 16 st * 4 dt = 2048
  int dt = blk & 3, st = (blk>>2) & 15, b = blk >> 6;
  int s0 = st*64, d0 = dt*64;
  int tid = threadIdx.x;
  for (int k=0;k<16;k++){
    int idx = k*256 + tid;
    int r = idx >> 6, c = idx & 63;
    size_t gi = ((size_t)b*TE + s0 + r)*DIM + d0 + c;
    float e = enc[gi];
    ls[r][c] = e + emb[gi];
    Eh[gi] = (_Float16)e;
  }
  __syncthreads();
  for (int k=0;k<16;k++){
    int idx = k*256 + tid;
    int r = idx >> 6, c = idx & 63;
    EVt[((size_t)b*DIM + d0 + r)*TE + s0 + c] = (_Float16)ls[c][r];
  }
}

// ---------- input linear + shift-right as fp16 MFMA: X = shift(mel) @ W_lin^T ----------
__global__ __launch_bounds__(256) void k_lin_mfma(const float* __restrict__ mel,
    const _Float16* __restrict__ Wh, const _Float16* __restrict__ Wl,
    const float* __restrict__ bias, _Float16* __restrict__ X)
{
  __shared__ __align__(16) _Float16 ms[64*104];   // 64 rows x 96 cols (pad 104)
  int blk = blockIdx.x;                 // 1024: 32 b x 32 t-tiles
  int b = blk >> 5;
  int t0 = (blk & 31) << 6;
  int tid = threadIdx.x;

  for (int i = tid; i < 64*12; i += 256){
    int row = i / 12, cg = (i - row*12) * 8;
    int t = t0 + row - 1;               // shifted: X[t] = lin(mel[t-1])
    f16x8 v = {};
    if (t >= 0 && cg < INDIM){
      const float4* p = (const float4*)(mel + ((size_t)b*TD + t)*INDIM + cg);
      float4 f0 = p[0], f1 = p[1];
      v[0]=(_Float16)f0.x; v[1]=(_Float16)f0.y; v[2]=(_Float16)f0.z; v[3]=(_Float16)f0.w;
      v[4]=(_Float16)f1.x; v[5]=(_Float16)f1.y; v[6]=(_Float16)f1.z; v[7]=(_Float16)f1.w;
    }
    *(f16x8*)&ms[row*104 + cg] = v;
  }
  __syncthreads();

  int wave = tid >> 6, lane = tid & 63;
  int l15 = lane & 15, l4 = lane >> 4;
  int mb = wave << 4;

  f16x8 am[3];
  #pragma unroll
  for (int kc=0;kc<3;kc++) am[kc] = *(f16x8*)&ms[(mb + l15)*104 + kc*32 + l4*8];

  for (int dt=0; dt<16; dt++){
    size_t wrow = (size_t)(dt*16 + l15)*96 + l4*8;
    f32x4 a = (f32x4){0.f,0.f,0.f,0.f};
    #pragma unroll
    for (int kc=0;kc<3;kc++){
      f16x8 bh = *(const f16x8*)(Wh + wrow + kc*32);
      f16x8 bl = *(const f16x8*)(Wl + wrow + kc*32);
      a = __builtin_amdgcn_mfma_f32_16x16x32_f16(am[kc], bh, a, 0,0,0);
      a = __builtin_amdgcn_mfma_f32_16x16x32_f16(am[kc], bl, a, 0,0,0);
    }
    int d = dt*16 + l15;
    float bv = bias[d];
    #pragma unroll
    for (int r=0;r<4;r++){
      int m = mb + l4*4 + r;
      int t = t0 + m;
      X[((size_t)b*TD + t)*DIM + d] = (t==0) ? (_Float16)0.f : (_Float16)(a[r] + bv);
    }
  }
}

// ---------------- conv-GLU as fp16 MFMA GEMM (d-pair: 64t x 128d per block) ----------
// Each A-fragment ds_read feeds 4 MFMAs (2 d-groups x 2 gates) -> LDS-read
// bytes per FLOP halved vs the 64x64 version; X staging traffic halved.
__global__ __launch_bounds__(256) void k_conv_mfma(const _Float16* __restrict__ Xin,
    const _Float16* __restrict__ Wf, const float* __restrict__ bias,
    _Float16* __restrict__ Hout)
{
  __shared__ __align__(16) _Float16 as[68*264];   // 35.9 KB
  int id = blockIdx.x;                 // 2048: (32b x 32 mtile) x 2 dpair
  int dpair = id & 1, mtile = id >> 1;
  int b = mtile >> 5;
  int t0 = (mtile & 31) << 6;
  int d0 = dpair << 7;                 // 0 or 128
  int tid = threadIdx.x;

  for (int i = tid; i < 68*32; i += 256){
    int row = i >> 5, cg = (i & 31) << 3;
    int t = t0 - 4 + row;
    f16x8 v = {};
    if (t >= 0)
      v = *(const f16x8*)(Xin + ((size_t)b*TD + t)*DIM + cg);
    *(f16x8*)&as[row*264 + cg] = v;
  }
  __syncthreads();

  int lane = tid & 63, wave = tid >> 6;
  int l15 = lane & 15, l4 = lane >> 4;
  int dA = d0 + (wave << 4) + l15;
  int dB = dA + 64;

  const _Float16* p0 = Wf + (size_t)dA*1280 + l4*8;          // a-gate, d
  const _Float16* p1 = Wf + (size_t)(256 + dA)*1280 + l4*8;  // g-gate, d
  const _Float16* p2 = Wf + (size_t)dB*1280 + l4*8;          // a-gate, d+64
  const _Float16* p3 = Wf + (size_t)(256 + dB)*1280 + l4*8;  // g-gate, d+64

  f32x4 ac0[4], ac1[4], ac2[4], ac3[4];
  #pragma unroll
  for (int mt=0;mt<4;mt++){
    ac0[mt]=(f32x4){0.f,0.f,0.f,0.f}; ac1[mt]=(f32x4){0.f,0.f,0.f,0.f};
    ac2[mt]=(f32x4){0.f,0.f,0.f,0.f}; ac3[mt]=(f32x4){0.f,0.f,0.f,0.f};
  }

  f16x8 b0v = *(const f16x8*)p0, b1v = *(const f16x8*)p1;
  f16x8 b2v = *(const f16x8*)p2, b3v = *(const f16x8*)p3;
  #pragma unroll
  for (int kc = 0; kc < 40; ++kc){
    f16x8 n0=b0v, n1=b1v, n2=b2v, n3=b3v;
    if (kc < 39){
      n0 = *(const f16x8*)(p0 + (kc+1)*32);
      n1 = *(const f16x8*)(p1 + (kc+1)*32);
      n2 = *(const f16x8*)(p2 + (kc+1)*32);
      n3 = *(const f16x8*)(p3 + (kc+1)*32);
    }
    int tap = kc >> 3;
    int ic0 = (kc & 7) << 5;
    int abase = (l15 + tap)*264 + ic0 + l4*8;
    #pragma unroll
    for (int mt=0;mt<4;mt++){
      f16x8 av = *(f16x8*)&as[abase + mt*16*264];
      ac0[mt] = __builtin_amdgcn_mfma_f32_16x16x32_f16(av, b0v, ac0[mt], 0,0,0);
      ac1[mt] = __builtin_amdgcn_mfma_f32_16x16x32_f16(av, b1v, ac1[mt], 0,0,0);
      ac2[mt] = __builtin_amdgcn_mfma_f32_16x16x32_f16(av, b2v, ac2[mt], 0,0,0);
      ac3[mt] = __builtin_amdgcn_mfma_f32_16x16x32_f16(av, b3v, ac3[mt], 0,0,0);
    }
    b0v=n0; b1v=n1; b2v=n2; b3v=n3;
  }

  const float is2 = 0.7071067811865476f;
  float ba0 = bias[dA], bg0 = bias[256 + dA];
  float ba1 = bias[dB], bg1 = bias[256 + dB];
  #pragma unroll
  for (int mt=0; mt<4; mt++){
    #pragma unroll
    for (int r=0;r<4;r++){
      int m = mt*16 + l4*4 + r;
      size_t orow = ((size_t)b*TD + t0 + m)*DIM;
      float xr0 = (float)as[(m+4)*264 + dA];
      float xr1 = (float)as[(m+4)*264 + dB];
      float a0 = ac0[mt][r] + ba0, g0 = ac1[mt][r] + bg0;
      float a1 = ac2[mt][r] + ba1, g1 = ac3[mt][r] + bg1;
      Hout[orow + dA] = (_Float16)((a0*sigmoidf_(g0) + xr0)*is2);
      Hout[orow + dB] = (_Float16)((a1*sigmoidf_(g1) + xr1)*is2);
    }
  }
}

// ---------- fused q-linear + flash attention + residual ----------
// R8 banked-best structure, byte-for-byte. H fp16 end-to-end.
__device__ __forceinline__ void stage_k(const _Float16* __restrict__ Ehb,
    _Float16* __restrict__ dst, int srow0, int wave, int lane)
{
  int r2 = lane >> 5, cu = lane & 31;
  #pragma unroll
  for (int ii=0; ii<8; ii++){
    int row = (ii*4 + wave)*2 + r2;                       // 0..63
    cp16(Ehb + (size_t)(srow0 + row)*DIM + ((cu ^ (row & 7)) << 3),
         dst + (ii*4 + wave)*512);                        // wave-uniform LDS base
  }
}

__global__ __launch_bounds__(256) void k_attn(_Float16* __restrict__ H,
    const _Float16* __restrict__ Wqh, const _Float16* __restrict__ Wql,
    const float* __restrict__ bq,
    const _Float16* __restrict__ Eh, const _Float16* __restrict__ EVt)
{
  __shared__ __align__(16) _Float16 Kb[2][64*256];   // 64 KB K double-buffer (swizzled)
  __shared__ __align__(16) _Float16 pb[64][72];      // 9.2 KB P chunk (cross-wave)
  __shared__ float alphas[64];
  __shared__ float linvs[64];

  int i = blockIdx.x;                   // XCD swizzle: same-batch blocks share an XCD
  int b = (i & 7) | ((i >> 8) << 3);
  int t0 = ((i >> 3) & 31) << 6;
  int tid = threadIdx.x;
  int wave = tid >> 6, lane = tid & 63;
  int l15 = lane & 15, l4 = lane >> 4;
  int mb = wave << 4;

  const _Float16* Ehb = Eh + (size_t)b*TE*DIM;
  const _Float16* EVb = EVt + (size_t)b*DIM*TE;

  // prefetch K chunk 0 into Kb[0] (latency hidden under the whole q-linear)
  stage_k(Ehb, &Kb[0][0], 0, wave, lane);

  // ---- q-linear (2-term fp16); H is fp16 -> direct fragment loads ----
  f16x8 ah[8];
  {
    const _Float16* hrow = H + ((size_t)b*TD + t0 + mb + l15)*DIM;
    #pragma unroll
    for (int kc=0;kc<8;kc++) ah[kc] = *(const f16x8*)(hrow + kc*32 + l4*8);
  }

  f32x4 qacc[16];
  for (int ot=0;ot<16;ot++){
    size_t wrow = (size_t)(ot*16 + l15)*256 + l4*8;
    f32x4 a = (f32x4){0.f,0.f,0.f,0.f};
    #pragma unroll
    for (int kc=0;kc<8;kc++){
      f16x8 bh = *(const f16x8*)(Wqh + wrow + kc*32);
      f16x8 bl = *(const f16x8*)(Wql + wrow + kc*32);
      a = __builtin_amdgcn_mfma_f32_16x16x32_f16(ah[kc], bh, a, 0,0,0);
      a = __builtin_amdgcn_mfma_f32_16x16x32_f16(ah[kc], bl, a, 0,0,0);
    }
    qacc[ot] = a;
  }
  #pragma unroll
  for (int ot=0;ot<16;ot++){
    float bqv = bq[ot*16 + l15];
    #pragma unroll
    for (int r=0;r<4;r++) qacc[ot][r] += bqv;
  }

  // ---- transit Q hi/lo through Kb[1] (one-time; done before Kb[1] is prefetched) ----
  #pragma unroll
  for (int ot=0;ot<16;ot++){
    int o = ot*16 + l15;
    #pragma unroll
    for (int r=0;r<4;r++)
      Kb[1][(mb + l4*4 + r)*256 + o] = (_Float16)qacc[ot][r];
  }
  __syncthreads();
  f16x8 aqh[8];
  #pragma unroll
  for (int kc=0;kc<8;kc++) aqh[kc] = *(f16x8*)&Kb[1][(mb + l15)*256 + kc*32 + l4*8];
  __syncthreads();
  #pragma unroll
  for (int ot=0;ot<16;ot++){
    int o = ot*16 + l15;
    #pragma unroll
    for (int r=0;r<4;r++){
      float v = qacc[ot][r];
      _Float16 h = (_Float16)v;
      Kb[1][(mb + l4*4 + r)*256 + o] = (_Float16)(v - (float)h);
    }
  }
  __syncthreads();
  f16x8 aql[8];
  #pragma unroll
  for (int kc=0;kc<8;kc++) aql[kc] = *(f16x8*)&Kb[1][(mb + l15)*256 + kc*32 + l4*8];
  __syncthreads();                       // Kb[1] free for prefetch from here on

  f32x4 oacc[4][4];                      // [m-tile][d-tile], d-split: this wave owns dq..dq+63
  #pragma unroll
  for (int mt=0;mt<4;mt++)
    #pragma unroll
    for (int dt=0;dt<4;dt++) oacc[mt][dt] = (f32x4){0.f,0.f,0.f,0.f};
  float mrun[4], lrun[4];
  #pragma unroll
  for (int r=0;r<4;r++){ mrun[r] = -3.0e38f; lrun[r] = 0.f; }
  int dq = wave << 6;
  int sw = l15 & 7;

  #pragma unroll 2
  for (int c = 0; c < 16; ++c){
    int cur = c & 1;
    int s0 = c << 6;
    // prefetch next K chunk into the other buffer; drains at loop-end barrier
    if (c < 15) stage_k(Ehb, &Kb[cur^1][0], s0 + 64, wave, lane);

    // ---- QK^T (reads swizzled Kb[cur]) ----
    f32x4 sacc[4];
    #pragma unroll
    for (int st=0;st<4;st++){
      const _Float16* kb = &Kb[cur][(st*16 + l15)*256];
      f32x4 a = (f32x4){0.f,0.f,0.f,0.f};
      #pragma unroll
      for (int kc=0;kc<8;kc++){
        f16x8 bh = *(const f16x8*)(kb + (((kc*4 + l4) ^ sw) << 3));
        a = __builtin_amdgcn_mfma_f32_16x16x32_f16(aqh[kc], bh, a, 0,0,0);
        a = __builtin_amdgcn_mfma_f32_16x16x32_f16(aql[kc], bh, a, 0,0,0);
      }
      sacc[st] = a;
    }

    // ---- V fragments for this wave's d-quarter, direct from global (L2) ----
    f16x8 vv[2][4];
    #pragma unroll
    for (int kp=0;kp<2;kp++)
      #pragma unroll
      for (int dt=0;dt<4;dt++)
        vv[kp][dt] = *(const f16x8*)(EVb + (size_t)(dq + dt*16 + l15)*TE + s0 + kp*32 + l4*8);

    // ---- online softmax (owner wave: rows mb..mb+15) ----
    float alpha[4];
    #pragma unroll
    for (int r=0;r<4;r++){
      float cm = fmaxf(fmaxf(sacc[0][r], sacc[1][r]), fmaxf(sacc[2][r], sacc[3][r]));
      cm = fmaxf(cm, __shfl_xor(cm, 1));
      cm = fmaxf(cm, __shfl_xor(cm, 2));
      cm = fmaxf(cm, __shfl_xor(cm, 4));
      cm = fmaxf(cm, __shfl_xor(cm, 8));
      float mnew = fmaxf(mrun[r], cm);
      alpha[r] = __expf(mrun[r] - mnew);
      mrun[r] = mnew;
      float ps = 0.f;
      #pragma unroll
      for (int st=0;st<4;st++){
        float p = __expf(sacc[st][r] - mnew);
        sacc[st][r] = p;
        ps += p;
      }
      ps += __shfl_xor(ps, 1);
      ps += __shfl_xor(ps, 2);
      ps += __shfl_xor(ps, 4);
      ps += __shfl_xor(ps, 8);
      lrun[r] = lrun[r]*alpha[r] + ps;
    }

    // ---- publish P and alpha ----
    #pragma unroll
    for (int st=0;st<4;st++)
      #pragma unroll
      for (int r=0;r<4;r++)
        pb[mb + l4*4 + r][st*16 + l15] = (_Float16)sacc[st][r];
    if (l15 == 0){
      #pragma unroll
      for (int r=0;r<4;r++) alphas[mb + l4*4 + r] = alpha[r];
    }
    // raw barrier: wait LDS writes only — K prefetch stays in flight (no vmcnt drain)
    asm volatile("s_waitcnt lgkmcnt(0)" ::: "memory");
    __builtin_amdgcn_s_barrier();

    // ---- rescale + PV (d-split: all 64 rows, this wave's 64 d-columns) ----
    #pragma unroll
    for (int mt=0;mt<4;mt++){
      #pragma unroll
      for (int r=0;r<4;r++){
        float av = alphas[mt*16 + l4*4 + r];
        #pragma unroll
        for (int dt=0;dt<4;dt++) oacc[mt][dt][r] *= av;
      }
    }
    #pragma unroll
    for (int kp=0;kp<2;kp++){
      f16x8 pa[4];
      #pragma unroll
      for (int mt=0;mt<4;mt++) pa[mt] = *(f16x8*)&pb[mt*16 + l15][kp*32 + l4*8];
      #pragma unroll
      for (int dt=0;dt<4;dt++){
        #pragma unroll
        for (int mt=0;mt<4;mt++)
          oacc[mt][dt] = __builtin_amdgcn_mfma_f32_16x16x32_f16(pa[mt], vv[kp][dt], oacc[mt][dt], 0,0,0);
      }
    }
    __syncthreads();   // pbuf reads done + K prefetch drained (vmcnt 0) before next chunk
  }

  // ---- epilogue: publish 1/l, then H += O/l (fp16 RMW; each wave its d-quarter) ----
  if (l15 == 0){
    #pragma unroll
    for (int r=0;r<4;r++) linvs[mb + l4*4 + r] = 1.f / lrun[r];
  }
  __syncthreads();
  #pragma unroll
  for (int mt=0;mt<4;mt++){
    #pragma unroll
    for (int r=0;r<4;r++){
      float li = linvs[mt*16 + l4*4 + r];
      int t = t0 + mt*16 + l4*4 + r;
      _Float16* hp = &H[((size_t)b*TD + t)*DIM + dq];
      #pragma unroll
      for (int dt=0;dt<4;dt++){
        int idx = dt*16 + l15;
        hp[idx] = (_Float16)((float)hp[idx] + oacc[mt][dt][r] * li);
      }
    }
  }
}

// ---------- output projection as fp16 MFMA: out = Pb @ (Wph+Wpl)^T + bias ----------
__global__ __launch_bounds__(256) void k_proj_mfma(const _Float16* __restrict__ Hin,
    const _Float16* __restrict__ Wh, const _Float16* __restrict__ Wl,
    const float* __restrict__ bias, float* __restrict__ out)
{
  int blk = blockIdx.x;                 // 1024: 32 b x 32 t-tiles
  int b = blk >> 5;
  int t0 = (blk & 31) << 6;
  int tid = threadIdx.x;
  int wave = tid >> 6, lane = tid & 63;
  int l15 = lane & 15, l4 = lane >> 4;
  int mb = wave << 4;

  f16x8 ah[8];
  const _Float16* hrow = Hin + ((size_t)b*TD + t0 + mb + l15)*DIM;
  #pragma unroll
  for (int kc=0;kc<8;kc++) ah[kc] = *(const f16x8*)(hrow + kc*32 + l4*8);

  #pragma unroll
  for (int nt=0; nt<5; nt++){
    size_t wrow = (size_t)(nt*16 + l15)*256 + l4*8;
    f32x4 a = (f32x4){0.f,0.f,0.f,0.f};
    #pragma unroll
    for (int kc=0;kc<8;kc++){
      f16x8 bh = *(const f16x8*)(Wh + wrow + kc*32);
      f16x8 bl = *(const f16x8*)(Wl + wrow + kc*32);
      a = __builtin_amdgcn_mfma_f32_16x16x32_f16(ah[kc], bh, a, 0,0,0);
      a = __builtin_amdgcn_mfma_f32_16x16x32_f16(ah[kc], bl, a, 0,0,0);
    }
    int n = nt*16 + l15;
    float bv = bias[n];
    #pragma unroll
    for (int r=0;r<4;r++){
      int t = t0 + mb + l4*4 + r;
      out[((size_t)b*TD + t)*INDIM + n] = a[r] + bv;
    }
  }
}

extern "C" void kernel_launch(void* const* d_in, const int* in_sizes, int n_in,
                              void* d_out, int out_size, void* d_ws, size_t ws_size,
                              hipStream_t stream) {
  const float* enc   = (const float*)d_in[0];
  const float* emb   = (const float*)d_in[1];
  const float* mel   = (const float*)d_in[2];
  const float* W_lin = (const float*)d_in[3];
  const float* b_lin = (const float*)d_in[4];
  const float* w0    = (const float*)d_in[5];
  const float* b0    = (const float*)d_in[6];
  const float* w1    = (const float*)d_in[7];
  const float* b1    = (const float*)d_in[8];
  const float* Wq    = (const float*)d_in[9];
  const float* bq    = (const float*)d_in[10];
  const float* Wp    = (const float*)d_in[11];
  const float* bp    = (const float*)d_in[12];
  float* out = (float*)d_out;

  const size_t NTOK = (size_t)BB*TD*DIM;           // 16.78M
  const size_t NE   = (size_t)BB*TE*DIM;           // 8.39M
  _Float16* Xb  = (_Float16*)d_ws;
  _Float16* H   = Xb + NTOK;                       // fp16 end-to-end
  _Float16* Wf0 = H + NTOK;
  _Float16* Wf1 = Wf0 + (size_t)512*1280;
  _Float16* Wqh = Wf1 + (size_t)512*1280;
  _Float16* Wql = Wqh + 65536;
  _Float16* Wlh = Wql + 65536;                     // 256*96
  _Float16* Wll = Wlh + 24576;
  _Float16* Wph = Wll + 24576;                     // 80*256
  _Float16* Wpl = Wph + 20480;
  _Float16* Eh  = Xb;                              // after conv0 consumes Xb
  _Float16* EVt = Xb + NE;
  _Float16* Pb  = Xb;                              // after attn consumes Eh/EVt

  k_prep     <<<5552, 256, 0, stream>>>(w0, w1, Wq, W_lin, Wp,
                                        Wf0, Wf1, Wqh, Wql, Wlh, Wll, Wph, Wpl);
  k_lin_mfma <<<1024, 256, 0, stream>>>(mel, Wlh, Wll, b_lin, Xb);
  k_conv_mfma<<<2048, 256, 0, stream>>>(Xb, Wf0, b0, H);
  k_eprep    <<<2048, 256, 0, stream>>>(enc, emb, Eh, EVt);
  k_attn     <<<1024, 256, 0, stream>>>(H, Wqh, Wql, bq, Eh, EVt);
  k_conv_mfma<<<2048, 256, 0, stream>>>(H, Wf1, b1, Pb);
  k_proj_mfma<<<1024, 256, 0, stream>>>(Pb, Wph, Wpl, bp, out);
}

// Round 10
// 838.255 us; speedup vs baseline: 1.0175x; 1.0175x over previous
//
#include <hip/hip_runtime.h>
#include <math.h>

#define BB 32
#define TD 2048
#define TE 1024
#define DIM 256
#define INDIM 80

typedef __attribute__((ext_vector_type(8))) _Float16 f16x8;
typedef __attribute__((ext_vector_type(4))) float f32x4;

__device__ __forceinline__ float sigmoidf_(float x){ return 1.f/(1.f+__expf(-x)); }

// async 16B global->LDS copy (direct DMA, no VGPR round-trip)
__device__ __forceinline__ void cp16(const _Float16* g, _Float16* l){
  __builtin_amdgcn_global_load_lds(
      (const __attribute__((address_space(1))) unsigned int*)g,
      (__attribute__((address_space(3))) unsigned int*)l, 16, 0, 0);
}

// ------- merged weight prep: conv reorders + 2-term fp16 splits, one launch -------
__global__ __launch_bounds__(256) void k_prep(
    const float* __restrict__ w0, const float* __restrict__ w1,
    const float* __restrict__ Wq, const float* __restrict__ Wl,
    const float* __restrict__ Wp,
    _Float16* __restrict__ Wf0, _Float16* __restrict__ Wf1,
    _Float16* __restrict__ Wqh, _Float16* __restrict__ Wql,
    _Float16* __restrict__ Wlh, _Float16* __restrict__ Wll,
    _Float16* __restrict__ Wph, _Float16* __restrict__ Wpl)
{
  int i = blockIdx.x*256 + threadIdx.x;
  if (i < 655360){
    int o = i / 1280, kk = i - o*1280;
    int tap = kk >> 8, ic = kk & 255;
    Wf0[i] = (_Float16)w0[(size_t)o*1280 + ic*5 + tap];
  } else if (i < 1310720){
    int j = i - 655360;
    int o = j / 1280, kk = j - o*1280;
    int tap = kk >> 8, ic = kk & 255;
    Wf1[j] = (_Float16)w1[(size_t)o*1280 + ic*5 + tap];
  } else if (i < 1376256){
    int j = i - 1310720;
    float f = Wq[j];
    _Float16 h = (_Float16)f;
    Wqh[j] = h; Wql[j] = (_Float16)(f - (float)h);
  } else if (i < 1400832){
    int j = i - 1376256;
    int d = j / 96, k = j - d*96;
    float f = (k < INDIM) ? Wl[d*INDIM + k] : 0.f;
    _Float16 h = (_Float16)f;
    Wlh[j] = h; Wll[j] = (_Float16)(f - (float)h);
  } else {
    int j = i - 1400832;
    float f = Wp[j];
    _Float16 h = (_Float16)f;
    Wph[j] = h; Wpl[j] = (_Float16)(f - (float)h);
  }
}

// ------- enc prep: Eh = fp16(enc) [b][s][d];  EVt = fp16(enc+emb) transposed [b][d][s] ---
__global__ __launch_bounds__(256) void k_eprep(const float* __restrict__ enc,
    const float* __restrict__ emb, _Float16* __restrict__ Eh,
    _Float16* __restrict__ EVt)
{
  __shared__ float ls[64][65];
  int blk = blockIdx.x;                  // 32 b * 16 st * 4 dt = 2048
  int dt = blk & 3, st = (blk>>2) & 15, b = blk >> 6;
  int s0 = st*64, d0 = dt*64;
  int tid = threadIdx.x;
  for (int k=0;k<16;k++){
    int idx = k*256 + tid;
    int r = idx >> 6, c = idx & 63;
    size_t gi = ((size_t)b*TE + s0 + r)*DIM + d0 + c;
    float e = enc[gi];
    ls[r][c] = e + emb[gi];
    Eh[gi] = (_Float16)e;
  }
  __syncthreads();
  for (int k=0;k<16;k++){
    int idx = k*256 + tid;
    int r = idx >> 6, c = idx & 63;
    EVt[((size_t)b*DIM + d0 + r)*TE + s0 + c] = (_Float16)ls[c][r];
  }
}

// ---------- input linear + shift-right as fp16 MFMA: X = shift(mel) @ W_lin^T ----------
__global__ __launch_bounds__(256) void k_lin_mfma(const float* __restrict__ mel,
    const _Float16* __restrict__ Wh, const _Float16* __restrict__ Wl,
    const float* __restrict__ bias, _Float16* __restrict__ X)
{
  __shared__ __align__(16) _Float16 ms[64*104];   // 64 rows x 96 cols (pad 104)
  int blk = blockIdx.x;                 // 1024: 32 b x 32 t-tiles
  int b = blk >> 5;
  int t0 = (blk & 31) << 6;
  int tid = threadIdx.x;

  for (int i = tid; i < 64*12; i += 256){
    int row = i / 12, cg = (i - row*12) * 8;
    int t = t0 + row - 1;               // shifted: X[t] = lin(mel[t-1])
    f16x8 v = {};
    if (t >= 0 && cg < INDIM){
      const float4* p = (const float4*)(mel + ((size_t)b*TD + t)*INDIM + cg);
      float4 f0 = p[0], f1 = p[1];
      v[0]=(_Float16)f0.x; v[1]=(_Float16)f0.y; v[2]=(_Float16)f0.z; v[3]=(_Float16)f0.w;
      v[4]=(_Float16)f1.x; v[5]=(_Float16)f1.y; v[6]=(_Float16)f1.z; v[7]=(_Float16)f1.w;
    }
    *(f16x8*)&ms[row*104 + cg] = v;
  }
  __syncthreads();

  int wave = tid >> 6, lane = tid & 63;
  int l15 = lane & 15, l4 = lane >> 4;
  int mb = wave << 4;

  f16x8 am[3];
  #pragma unroll
  for (int kc=0;kc<3;kc++) am[kc] = *(f16x8*)&ms[(mb + l15)*104 + kc*32 + l4*8];

  for (int dt=0; dt<16; dt++){
    size_t wrow = (size_t)(dt*16 + l15)*96 + l4*8;
    f32x4 a = (f32x4){0.f,0.f,0.f,0.f};
    #pragma unroll
    for (int kc=0;kc<3;kc++){
      f16x8 bh = *(const f16x8*)(Wh + wrow + kc*32);
      f16x8 bl = *(const f16x8*)(Wl + wrow + kc*32);
      a = __builtin_amdgcn_mfma_f32_16x16x32_f16(am[kc], bh, a, 0,0,0);
      a = __builtin_amdgcn_mfma_f32_16x16x32_f16(am[kc], bl, a, 0,0,0);
    }
    int d = dt*16 + l15;
    float bv = bias[d];
    #pragma unroll
    for (int r=0;r<4;r++){
      int m = mb + l4*4 + r;
      int t = t0 + m;
      X[((size_t)b*TD + t)*DIM + d] = (t==0) ? (_Float16)0.f : (_Float16)(a[r] + bv);
    }
  }
}

// ---------------- conv-GLU as fp16 MFMA GEMM (64t x 64d, weight prefetch depth 2) ----
// R8's proven 64x64 shape; only change: the L2 weight stream is prefetched TWO
// kc-iterations ahead (+16 VGPR) to cover ~200cyc L2 latency (1-deep covered ~80).
__global__ __launch_bounds__(256) void k_conv_mfma(const _Float16* __restrict__ Xin,
    const _Float16* __restrict__ Wf, const float* __restrict__ bias,
    _Float16* __restrict__ Hout)
{
  __shared__ __align__(16) _Float16 as[68*264];   // 35.9 KB
  int id = blockIdx.x;
  int dtile = id & 3, mtile = id >> 2;
  int b = mtile >> 5;
  int t0 = (mtile & 31) << 6;
  int d0 = dtile << 6;
  int tid = threadIdx.x;

  for (int i = tid; i < 68*32; i += 256){
    int row = i >> 5, cg = (i & 31) << 3;
    int t = t0 - 4 + row;
    f16x8 v = {};
    if (t >= 0)
      v = *(const f16x8*)(Xin + ((size_t)b*TD + t)*DIM + cg);
    *(f16x8*)&as[row*264 + cg] = v;
  }
  __syncthreads();

  int lane = tid & 63, wave = tid >> 6;
  int l15 = lane & 15, l4 = lane >> 4;
  int dA = d0 + (wave << 4) + l15;

  const _Float16* pA = Wf + (size_t)dA*1280 + l4*8;
  const _Float16* pG = Wf + (size_t)(256 + dA)*1280 + l4*8;

  f32x4 aca[4], acg[4];
  #pragma unroll
  for (int mt=0;mt<4;mt++){ aca[mt]=(f32x4){0.f,0.f,0.f,0.f}; acg[mt]=(f32x4){0.f,0.f,0.f,0.f}; }

  // weight stream, 2-deep prefetch: a0/g0 = kc, a1/g1 = kc+1, issue kc+2 each iter
  f16x8 a0 = *(const f16x8*)pA;
  f16x8 g0 = *(const f16x8*)pG;
  f16x8 a1 = *(const f16x8*)(pA + 32);
  f16x8 g1 = *(const f16x8*)(pG + 32);
  #pragma unroll
  for (int kc = 0; kc < 40; ++kc){
    f16x8 a2 = a1, g2 = g1;
    if (kc < 38){
      a2 = *(const f16x8*)(pA + (kc+2)*32);
      g2 = *(const f16x8*)(pG + (kc+2)*32);
    }
    int tap = kc >> 3;
    int ic0 = (kc & 7) << 5;
    int abase = (l15 + tap)*264 + ic0 + l4*8;
    #pragma unroll
    for (int mt=0;mt<4;mt++){
      f16x8 av = *(f16x8*)&as[abase + mt*16*264];
      aca[mt] = __builtin_amdgcn_mfma_f32_16x16x32_f16(av, a0, aca[mt], 0,0,0);
      acg[mt] = __builtin_amdgcn_mfma_f32_16x16x32_f16(av, g0, acg[mt], 0,0,0);
    }
    a0 = a1; g0 = g1; a1 = a2; g1 = g2;
  }

  const float is2 = 0.7071067811865476f;
  float ba = bias[dA], bg = bias[256 + dA];
  #pragma unroll
  for (int mt=0; mt<4; mt++){
    #pragma unroll
    for (int r=0;r<4;r++){
      int m = mt*16 + l4*4 + r;
      size_t orow = ((size_t)b*TD + t0 + m)*DIM;
      float xr = (float)as[(m+4)*264 + dA];
      float a = aca[mt][r] + ba;
      float g = acg[mt][r] + bg;
      Hout[orow + dA] = (_Float16)((a*sigmoidf_(g) + xr)*is2);
    }
  }
}

// ---------- fused q-linear + flash attention + residual ----------
// R8 banked-best structure, byte-for-byte. H fp16 end-to-end.
__device__ __forceinline__ void stage_k(const _Float16* __restrict__ Ehb,
    _Float16* __restrict__ dst, int srow0, int wave, int lane)
{
  int r2 = lane >> 5, cu = lane & 31;
  #pragma unroll
  for (int ii=0; ii<8; ii++){
    int row = (ii*4 + wave)*2 + r2;                       // 0..63
    cp16(Ehb + (size_t)(srow0 + row)*DIM + ((cu ^ (row & 7)) << 3),
         dst + (ii*4 + wave)*512);                        // wave-uniform LDS base
  }
}

__global__ __launch_bounds__(256) void k_attn(_Float16* __restrict__ H,
    const _Float16* __restrict__ Wqh, const _Float16* __restrict__ Wql,
    const float* __restrict__ bq,
    const _Float16* __restrict__ Eh, const _Float16* __restrict__ EVt)
{
  __shared__ __align__(16) _Float16 Kb[2][64*256];   // 64 KB K double-buffer (swizzled)
  __shared__ __align__(16) _Float16 pb[64][72];      // 9.2 KB P chunk (cross-wave)
  __shared__ float alphas[64];
  __shared__ float linvs[64];

  int i = blockIdx.x;                   // XCD swizzle: same-batch blocks share an XCD
  int b = (i & 7) | ((i >> 8) << 3);
  int t0 = ((i >> 3) & 31) << 6;
  int tid = threadIdx.x;
  int wave = tid >> 6, lane = tid & 63;
  int l15 = lane & 15, l4 = lane >> 4;
  int mb = wave << 4;

  const _Float16* Ehb = Eh + (size_t)b*TE*DIM;
  const _Float16* EVb = EVt + (size_t)b*DIM*TE;

  // prefetch K chunk 0 into Kb[0] (latency hidden under the whole q-linear)
  stage_k(Ehb, &Kb[0][0], 0, wave, lane);

  // ---- q-linear (2-term fp16); H is fp16 -> direct fragment loads ----
  f16x8 ah[8];
  {
    const _Float16* hrow = H + ((size_t)b*TD + t0 + mb + l15)*DIM;
    #pragma unroll
    for (int kc=0;kc<8;kc++) ah[kc] = *(const f16x8*)(hrow + kc*32 + l4*8);
  }

  f32x4 qacc[16];
  for (int ot=0;ot<16;ot++){
    size_t wrow = (size_t)(ot*16 + l15)*256 + l4*8;
    f32x4 a = (f32x4){0.f,0.f,0.f,0.f};
    #pragma unroll
    for (int kc=0;kc<8;kc++){
      f16x8 bh = *(const f16x8*)(Wqh + wrow + kc*32);
      f16x8 bl = *(const f16x8*)(Wql + wrow + kc*32);
      a = __builtin_amdgcn_mfma_f32_16x16x32_f16(ah[kc], bh, a, 0,0,0);
      a = __builtin_amdgcn_mfma_f32_16x16x32_f16(ah[kc], bl, a, 0,0,0);
    }
    qacc[ot] = a;
  }
  #pragma unroll
  for (int ot=0;ot<16;ot++){
    float bqv = bq[ot*16 + l15];
    #pragma unroll
    for (int r=0;r<4;r++) qacc[ot][r] += bqv;
  }

  // ---- transit Q hi/lo through Kb[1] (one-time; done before Kb[1] is prefetched) ----
  #pragma unroll
  for (int ot=0;ot<16;ot++){
    int o = ot*16 + l15;
    #pragma unroll
    for (int r=0;r<4;r++)
      Kb[1][(mb + l4*4 + r)*256 + o] = (_Float16)qacc[ot][r];
  }
  __syncthreads();
  f16x8 aqh[8];
  #pragma unroll
  for (int kc=0;kc<8;kc++) aqh[kc] = *(f16x8*)&Kb[1][(mb + l15)*256 + kc*32 + l4*8];
  __syncthreads();
  #pragma unroll
  for (int ot=0;ot<16;ot++){
    int o = ot*16 + l15;
    #pragma unroll
    for (int r=0;r<4;r++){
      float v = qacc[ot][r];
      _Float16 h = (_Float16)v;
      Kb[1][(mb + l4*4 + r)*256 + o] = (_Float16)(v - (float)h);
    }
  }
  __syncthreads();
  f16x8 aql[8];
  #pragma unroll
  for (int kc=0;kc<8;kc++) aql[kc] = *(f16x8*)&Kb[1][(mb + l15)*256 + kc*32 + l4*8];
  __syncthreads();                       // Kb[1] free for prefetch from here on

  f32x4 oacc[4][4];                      // [m-tile][d-tile], d-split: this wave owns dq..dq+63
  #pragma unroll
  for (int mt=0;mt<4;mt++)
    #pragma unroll
    for (int dt=0;dt<4;dt++) oacc[mt][dt] = (f32x4){0.f,0.f,0.f,0.f};
  float mrun[4], lrun[4];
  #pragma unroll
  for (int r=0;r<4;r++){ mrun[r] = -3.0e38f; lrun[r] = 0.f; }
  int dq = wave << 6;
  int sw = l15 & 7;

  #pragma unroll 2
  for (int c = 0; c < 16; ++c){
    int cur = c & 1;
    int s0 = c << 6;
    // prefetch next K chunk into the other buffer; drains at loop-end barrier
    if (c < 15) stage_k(Ehb, &Kb[cur^1][0], s0 + 64, wave, lane);

    // ---- QK^T (reads swizzled Kb[cur]) ----
    f32x4 sacc[4];
    #pragma unroll
    for (int st=0;st<4;st++){
      const _Float16* kb = &Kb[cur][(st*16 + l15)*256];
      f32x4 a = (f32x4){0.f,0.f,0.f,0.f};
      #pragma unroll
      for (int kc=0;kc<8;kc++){
        f16x8 bh = *(const f16x8*)(kb + (((kc*4 + l4) ^ sw) << 3));
        a = __builtin_amdgcn_mfma_f32_16x16x32_f16(aqh[kc], bh, a, 0,0,0);
        a = __builtin_amdgcn_mfma_f32_16x16x32_f16(aql[kc], bh, a, 0,0,0);
      }
      sacc[st] = a;
    }

    // ---- V fragments for this wave's d-quarter, direct from global (L2) ----
    f16x8 vv[2][4];
    #pragma unroll
    for (int kp=0;kp<2;kp++)
      #pragma unroll
      for (int dt=0;dt<4;dt++)
        vv[kp][dt] = *(const f16x8*)(EVb + (size_t)(dq + dt*16 + l15)*TE + s0 + kp*32 + l4*8);

    // ---- online softmax (owner wave: rows mb..mb+15) ----
    float alpha[4];
    #pragma unroll
    for (int r=0;r<4;r++){
      float cm = fmaxf(fmaxf(sacc[0][r], sacc[1][r]), fmaxf(sacc[2][r], sacc[3][r]));
      cm = fmaxf(cm, __shfl_xor(cm, 1));
      cm = fmaxf(cm, __shfl_xor(cm, 2));
      cm = fmaxf(cm, __shfl_xor(cm, 4));
      cm = fmaxf(cm, __shfl_xor(cm, 8));
      float mnew = fmaxf(mrun[r], cm);
      alpha[r] = __expf(mrun[r] - mnew);
      mrun[r] = mnew;
      float ps = 0.f;
      #pragma unroll
      for (int st=0;st<4;st++){
        float p = __expf(sacc[st][r] - mnew);
        sacc[st][r] = p;
        ps += p;
      }
      ps += __shfl_xor(ps, 1);
      ps += __shfl_xor(ps, 2);
      ps += __shfl_xor(ps, 4);
      ps += __shfl_xor(ps, 8);
      lrun[r] = lrun[r]*alpha[r] + ps;
    }

    // ---- publish P and alpha ----
    #pragma unroll
    for (int st=0;st<4;st++)
      #pragma unroll
      for (int r=0;r<4;r++)
        pb[mb + l4*4 + r][st*16 + l15] = (_Float16)sacc[st][r];
    if (l15 == 0){
      #pragma unroll
      for (int r=0;r<4;r++) alphas[mb + l4*4 + r] = alpha[r];
    }
    // raw barrier: wait LDS writes only — K prefetch stays in flight (no vmcnt drain)
    asm volatile("s_waitcnt lgkmcnt(0)" ::: "memory");
    __builtin_amdgcn_s_barrier();

    // ---- rescale + PV (d-split: all 64 rows, this wave's 64 d-columns) ----
    #pragma unroll
    for (int mt=0;mt<4;mt++){
      #pragma unroll
      for (int r=0;r<4;r++){
        float av = alphas[mt*16 + l4*4 + r];
        #pragma unroll
        for (int dt=0;dt<4;dt++) oacc[mt][dt][r] *= av;
      }
    }
    #pragma unroll
    for (int kp=0;kp<2;kp++){
      f16x8 pa[4];
      #pragma unroll
      for (int mt=0;mt<4;mt++) pa[mt] = *(f16x8*)&pb[mt*16 + l15][kp*32 + l4*8];
      #pragma unroll
      for (int dt=0;dt<4;dt++){
        #pragma unroll
        for (int mt=0;mt<4;mt++)
          oacc[mt][dt] = __builtin_amdgcn_mfma_f32_16x16x32_f16(pa[mt], vv[kp][dt], oacc[mt][dt], 0,0,0);
      }
    }
    __syncthreads();   // pbuf reads done + K prefetch drained (vmcnt 0) before next chunk
  }

  // ---- epilogue: publish 1/l, then H += O/l (fp16 RMW; each wave its d-quarter) ----
  if (l15 == 0){
    #pragma unroll
    for (int r=0;r<4;r++) linvs[mb + l4*4 + r] = 1.f / lrun[r];
  }
  __syncthreads();
  #pragma unroll
  for (int mt=0;mt<4;mt++){
    #pragma unroll
    for (int r=0;r<4;r++){
      float li = linvs[mt*16 + l4*4 + r];
      int t = t0 + mt*16 + l4*4 + r;
      _Float16* hp = &H[((size_t)b*TD + t)*DIM + dq];
      #pragma unroll
      for (int dt=0;dt<4;dt++){
        int idx = dt*16 + l15;
        hp[idx] = (_Float16)((float)hp[idx] + oacc[mt][dt][r] * li);
      }
    }
  }
}

// ---------- output projection as fp16 MFMA: out = Pb @ (Wph+Wpl)^T + bias ----------
__global__ __launch_bounds__(256) void k_proj_mfma(const _Float16* __restrict__ Hin,
    const _Float16* __restrict__ Wh, const _Float16* __restrict__ Wl,
    const float* __restrict__ bias, float* __restrict__ out)
{
  int blk = blockIdx.x;                 // 1024: 32 b x 32 t-tiles
  int b = blk >> 5;
  int t0 = (blk & 31) << 6;
  int tid = threadIdx.x;
  int wave = tid >> 6, lane = tid & 63;
  int l15 = lane & 15, l4 = lane >> 4;
  int mb = wave << 4;

  f16x8 ah[8];
  const _Float16* hrow = Hin + ((size_t)b*TD + t0 + mb + l15)*DIM;
  #pragma unroll
  for (int kc=0;kc<8;kc++) ah[kc] = *(const f16x8*)(hrow + kc*32 + l4*8);

  #pragma unroll
  for (int nt=0; nt<5; nt++){
    size_t wrow = (size_t)(nt*16 + l15)*256 + l4*8;
    f32x4 a = (f32x4){0.f,0.f,0.f,0.f};
    #pragma unroll
    for (int kc=0;kc<8;kc++){
      f16x8 bh = *(const f16x8*)(Wh + wrow + kc*32);
      f16x8 bl = *(const f16x8*)(Wl + wrow + kc*32);
      a = __builtin_amdgcn_mfma_f32_16x16x32_f16(ah[kc], bh, a, 0,0,0);
      a = __builtin_amdgcn_mfma_f32_16x16x32_f16(ah[kc], bl, a, 0,0,0);
    }
    int n = nt*16 + l15;
    float bv = bias[n];
    #pragma unroll
    for (int r=0;r<4;r++){
      int t = t0 + mb + l4*4 + r;
      out[((size_t)b*TD + t)*INDIM + n] = a[r] + bv;
    }
  }
}

extern "C" void kernel_launch(void* const* d_in, const int* in_sizes, int n_in,
                              void* d_out, int out_size, void* d_ws, size_t ws_size,
                              hipStream_t stream) {
  const float* enc   = (const float*)d_in[0];
  const float* emb   = (const float*)d_in[1];
  const float* mel   = (const float*)d_in[2];
  const float* W_lin = (const float*)d_in[3];
  const float* b_lin = (const float*)d_in[4];
  const float* w0    = (const float*)d_in[5];
  const float* b0    = (const float*)d_in[6];
  const float* w1    = (const float*)d_in[7];
  const float* b1    = (const float*)d_in[8];
  const float* Wq    = (const float*)d_in[9];
  const float* bq    = (const float*)d_in[10];
  const float* Wp    = (const float*)d_in[11];
  const float* bp    = (const float*)d_in[12];
  float* out = (float*)d_out;

  const size_t NTOK = (size_t)BB*TD*DIM;           // 16.78M
  const size_t NE   = (size_t)BB*TE*DIM;           // 8.39M
  _Float16* Xb  = (_Float16*)d_ws;
  _Float16* H   = Xb + NTOK;                       // fp16 end-to-end
  _Float16* Wf0 = H + NTOK;
  _Float16* Wf1 = Wf0 + (size_t)512*1280;
  _Float16* Wqh = Wf1 + (size_t)512*1280;
  _Float16* Wql = Wqh + 65536;
  _Float16* Wlh = Wql + 65536;                     // 256*96
  _Float16* Wll = Wlh + 24576;
  _Float16* Wph = Wll + 24576;                     // 80*256
  _Float16* Wpl = Wph + 20480;
  _Float16* Eh  = Xb;                              // after conv0 consumes Xb
  _Float16* EVt = Xb + NE;
  _Float16* Pb  = Xb;                              // after attn consumes Eh/EVt

  k_prep     <<<5552, 256, 0, stream>>>(w0, w1, Wq, W_lin, Wp,
                                        Wf0, Wf1, Wqh, Wql, Wlh, Wll, Wph, Wpl);
  k_lin_mfma <<<1024, 256, 0, stream>>>(mel, Wlh, Wll, b_lin, Xb);
  k_conv_mfma<<<4096, 256, 0, stream>>>(Xb, Wf0, b0, H);
  k_eprep    <<<2048, 256, 0, stream>>>(enc, emb, Eh, EVt);
  k_attn     <<<1024, 256, 0, stream>>>(H, Wqh, Wql, bq, Eh, EVt);
  k_conv_mfma<<<4096, 256, 0, stream>>>(H, Wf1, b1, Pb);
  k_proj_mfma<<<1024, 256, 0, stream>>>(Pb, Wph, Wpl, bp, out);
}

// Round 11
// 744.105 us; speedup vs baseline: 1.1462x; 1.1265x over previous
//
#include <hip/hip_runtime.h>
#include <math.h>

#define BB 32
#define TD 2048
#define TE 1024
#define DIM 256
#define INDIM 80

typedef __attribute__((ext_vector_type(8))) _Float16 f16x8;
typedef __attribute__((ext_vector_type(4))) float f32x4;

__device__ __forceinline__ float sigmoidf_(float x){ return 1.f/(1.f+__expf(-x)); }

// async 16B global->LDS copy (direct DMA, no VGPR round-trip)
__device__ __forceinline__ void cp16(const _Float16* g, _Float16* l){
  __builtin_amdgcn_global_load_lds(
      (const __attribute__((address_space(1))) unsigned int*)g,
      (__attribute__((address_space(3))) unsigned int*)l, 16, 0, 0);
}

// ------- merged weight prep: conv reorders + 2-term fp16 splits, one launch -------
__global__ __launch_bounds__(256) void k_prep(
    const float* __restrict__ w0, const float* __restrict__ w1,
    const float* __restrict__ Wq, const float* __restrict__ Wl,
    const float* __restrict__ Wp,
    _Float16* __restrict__ Wf0, _Float16* __restrict__ Wf1,
    _Float16* __restrict__ Wqh, _Float16* __restrict__ Wql,
    _Float16* __restrict__ Wlh, _Float16* __restrict__ Wll,
    _Float16* __restrict__ Wph, _Float16* __restrict__ Wpl)
{
  int i = blockIdx.x*256 + threadIdx.x;
  if (i < 655360){
    int o = i / 1280, kk = i - o*1280;
    int tap = kk >> 8, ic = kk & 255;
    Wf0[i] = (_Float16)w0[(size_t)o*1280 + ic*5 + tap];
  } else if (i < 1310720){
    int j = i - 655360;
    int o = j / 1280, kk = j - o*1280;
    int tap = kk >> 8, ic = kk & 255;
    Wf1[j] = (_Float16)w1[(size_t)o*1280 + ic*5 + tap];
  } else if (i < 1376256){
    int j = i - 1310720;
    float f = Wq[j];
    _Float16 h = (_Float16)f;
    Wqh[j] = h; Wql[j] = (_Float16)(f - (float)h);
  } else if (i < 1400832){
    int j = i - 1376256;
    int d = j / 96, k = j - d*96;
    float f = (k < INDIM) ? Wl[d*INDIM + k] : 0.f;
    _Float16 h = (_Float16)f;
    Wlh[j] = h; Wll[j] = (_Float16)(f - (float)h);
  } else {
    int j = i - 1400832;
    float f = Wp[j];
    _Float16 h = (_Float16)f;
    Wph[j] = h; Wpl[j] = (_Float16)(f - (float)h);
  }
}

// ------- enc prep: Eh = fp16(enc) [b][s][d];  EVt = fp16(enc+emb) transposed [b][d][s] ---
__global__ __launch_bounds__(256) void k_eprep(const float* __restrict__ enc,
    const float* __restrict__ emb, _Float16* __restrict__ Eh,
    _Float16* __restrict__ EVt)
{
  __shared__ float ls[64][65];
  int blk = blockIdx.x;                  // 32 b * 16 st * 4 dt = 2048
  int dt = blk & 3, st = (blk>>2) & 15, b = blk >> 6;
  int s0 = st*64, d0 = dt*64;
  int tid = threadIdx.x;
  for (int k=0;k<16;k++){
    int idx = k*256 + tid;
    int r = idx >> 6, c = idx & 63;
    size_t gi = ((size_t)b*TE + s0 + r)*DIM + d0 + c;
    float e = enc[gi];
    ls[r][c] = e + emb[gi];
    Eh[gi] = (_Float16)e;
  }
  __syncthreads();
  for (int k=0;k<16;k++){
    int idx = k*256 + tid;
    int r = idx >> 6, c = idx & 63;
    EVt[((size_t)b*DIM + d0 + r)*TE + s0 + c] = (_Float16)ls[c][r];
  }
}

// ---------- input linear + shift-right as fp16 MFMA: X = shift(mel) @ W_lin^T ----------
__global__ __launch_bounds__(256) void k_lin_mfma(const float* __restrict__ mel,
    const _Float16* __restrict__ Wh, const _Float16* __restrict__ Wl,
    const float* __restrict__ bias, _Float16* __restrict__ X)
{
  __shared__ __align__(16) _Float16 ms[64*104];   // 64 rows x 96 cols (pad 104)
  int blk = blockIdx.x;                 // 1024: 32 b x 32 t-tiles
  int b = blk >> 5;
  int t0 = (blk & 31) << 6;
  int tid = threadIdx.x;

  for (int i = tid; i < 64*12; i += 256){
    int row = i / 12, cg = (i - row*12) * 8;
    int t = t0 + row - 1;               // shifted: X[t] = lin(mel[t-1])
    f16x8 v = {};
    if (t >= 0 && cg < INDIM){
      const float4* p = (const float4*)(mel + ((size_t)b*TD + t)*INDIM + cg);
      float4 f0 = p[0], f1 = p[1];
      v[0]=(_Float16)f0.x; v[1]=(_Float16)f0.y; v[2]=(_Float16)f0.z; v[3]=(_Float16)f0.w;
      v[4]=(_Float16)f1.x; v[5]=(_Float16)f1.y; v[6]=(_Float16)f1.z; v[7]=(_Float16)f1.w;
    }
    *(f16x8*)&ms[row*104 + cg] = v;
  }
  __syncthreads();

  int wave = tid >> 6, lane = tid & 63;
  int l15 = lane & 15, l4 = lane >> 4;
  int mb = wave << 4;

  f16x8 am[3];
  #pragma unroll
  for (int kc=0;kc<3;kc++) am[kc] = *(f16x8*)&ms[(mb + l15)*104 + kc*32 + l4*8];

  for (int dt=0; dt<16; dt++){
    size_t wrow = (size_t)(dt*16 + l15)*96 + l4*8;
    f32x4 a = (f32x4){0.f,0.f,0.f,0.f};
    #pragma unroll
    for (int kc=0;kc<3;kc++){
      f16x8 bh = *(const f16x8*)(Wh + wrow + kc*32);
      f16x8 bl = *(const f16x8*)(Wl + wrow + kc*32);
      a = __builtin_amdgcn_mfma_f32_16x16x32_f16(am[kc], bh, a, 0,0,0);
      a = __builtin_amdgcn_mfma_f32_16x16x32_f16(am[kc], bl, a, 0,0,0);
    }
    int d = dt*16 + l15;
    float bv = bias[d];
    #pragma unroll
    for (int r=0;r<4;r++){
      int m = mb + l4*4 + r;
      int t = t0 + m;
      X[((size_t)b*TD + t)*DIM + d] = (t==0) ? (_Float16)0.f : (_Float16)(a[r] + bv);
    }
  }
}

// ------- conv-GLU as fp16 MFMA GEMM (128t x 64d per block, weight prefetch 2) -------
// M-tile doubled vs R10: each weight fetch feeds 16 MFMAs (was 8) -> L2 weight
// stream halves (1.34 -> 0.67 GB/layer). Staging 132x264 = 69.7 KB -> 2 blocks/CU.
__global__ __launch_bounds__(256) void k_conv_mfma(const _Float16* __restrict__ Xin,
    const _Float16* __restrict__ Wf, const float* __restrict__ bias,
    _Float16* __restrict__ Hout)
{
  __shared__ __align__(16) _Float16 as[132*264];  // 69.7 KB
  int id = blockIdx.x;                 // 2048: 32b x 16 mtile x 4 dtile
  int dtile = id & 3;
  int mtile = (id >> 2) & 15;
  int b = id >> 6;
  int t0 = mtile << 7;
  int d0 = dtile << 6;
  int tid = threadIdx.x;

  for (int i = tid; i < 132*32; i += 256){
    int row = i >> 5, cg = (i & 31) << 3;
    int t = t0 - 4 + row;
    f16x8 v = {};
    if (t >= 0)
      v = *(const f16x8*)(Xin + ((size_t)b*TD + t)*DIM + cg);
    *(f16x8*)&as[row*264 + cg] = v;
  }
  __syncthreads();

  int lane = tid & 63, wave = tid >> 6;
  int l15 = lane & 15, l4 = lane >> 4;
  int dA = d0 + (wave << 4) + l15;

  const _Float16* pA = Wf + (size_t)dA*1280 + l4*8;
  const _Float16* pG = Wf + (size_t)(256 + dA)*1280 + l4*8;

  f32x4 aca[8], acg[8];
  #pragma unroll
  for (int mt=0;mt<8;mt++){ aca[mt]=(f32x4){0.f,0.f,0.f,0.f}; acg[mt]=(f32x4){0.f,0.f,0.f,0.f}; }

  // weight stream, 2-deep prefetch
  f16x8 a0 = *(const f16x8*)pA;
  f16x8 g0 = *(const f16x8*)pG;
  f16x8 a1 = *(const f16x8*)(pA + 32);
  f16x8 g1 = *(const f16x8*)(pG + 32);
  #pragma unroll
  for (int kc = 0; kc < 40; ++kc){
    f16x8 a2 = a1, g2 = g1;
    if (kc < 38){
      a2 = *(const f16x8*)(pA + (kc+2)*32);
      g2 = *(const f16x8*)(pG + (kc+2)*32);
    }
    int tap = kc >> 3;
    int ic0 = (kc & 7) << 5;
    int abase = (l15 + tap)*264 + ic0 + l4*8;
    #pragma unroll
    for (int mt=0;mt<8;mt++){
      f16x8 av = *(f16x8*)&as[abase + mt*16*264];
      aca[mt] = __builtin_amdgcn_mfma_f32_16x16x32_f16(av, a0, aca[mt], 0,0,0);
      acg[mt] = __builtin_amdgcn_mfma_f32_16x16x32_f16(av, g0, acg[mt], 0,0,0);
    }
    a0 = a1; g0 = g1; a1 = a2; g1 = g2;
  }

  const float is2 = 0.7071067811865476f;
  float ba = bias[dA], bg = bias[256 + dA];
  #pragma unroll
  for (int mt=0; mt<8; mt++){
    #pragma unroll
    for (int r=0;r<4;r++){
      int m = mt*16 + l4*4 + r;
      size_t orow = ((size_t)b*TD + t0 + m)*DIM;
      float xr = (float)as[(m+4)*264 + dA];
      float a = aca[mt][r] + ba;
      float g = acg[mt][r] + bg;
      Hout[orow + dA] = (_Float16)((a*sigmoidf_(g) + xr)*is2);
    }
  }
}

// ---------- fused q-linear + flash attention + residual ----------
// R8/R10 banked-best structure, byte-for-byte. H fp16 end-to-end.
__device__ __forceinline__ void stage_k(const _Float16* __restrict__ Ehb,
    _Float16* __restrict__ dst, int srow0, int wave, int lane)
{
  int r2 = lane >> 5, cu = lane & 31;
  #pragma unroll
  for (int ii=0; ii<8; ii++){
    int row = (ii*4 + wave)*2 + r2;                       // 0..63
    cp16(Ehb + (size_t)(srow0 + row)*DIM + ((cu ^ (row & 7)) << 3),
         dst + (ii*4 + wave)*512);                        // wave-uniform LDS base
  }
}

__global__ __launch_bounds__(256) void k_attn(_Float16* __restrict__ H,
    const _Float16* __restrict__ Wqh, const _Float16* __restrict__ Wql,
    const float* __restrict__ bq,
    const _Float16* __restrict__ Eh, const _Float16* __restrict__ EVt)
{
  __shared__ __align__(16) _Float16 Kb[2][64*256];   // 64 KB K double-buffer (swizzled)
  __shared__ __align__(16) _Float16 pb[64][72];      // 9.2 KB P chunk (cross-wave)
  __shared__ float alphas[64];
  __shared__ float linvs[64];

  int i = blockIdx.x;                   // XCD swizzle: same-batch blocks share an XCD
  int b = (i & 7) | ((i >> 8) << 3);
  int t0 = ((i >> 3) & 31) << 6;
  int tid = threadIdx.x;
  int wave = tid >> 6, lane = tid & 63;
  int l15 = lane & 15, l4 = lane >> 4;
  int mb = wave << 4;

  const _Float16* Ehb = Eh + (size_t)b*TE*DIM;
  const _Float16* EVb = EVt + (size_t)b*DIM*TE;

  // prefetch K chunk 0 into Kb[0] (latency hidden under the whole q-linear)
  stage_k(Ehb, &Kb[0][0], 0, wave, lane);

  // ---- q-linear (2-term fp16); H is fp16 -> direct fragment loads ----
  f16x8 ah[8];
  {
    const _Float16* hrow = H + ((size_t)b*TD + t0 + mb + l15)*DIM;
    #pragma unroll
    for (int kc=0;kc<8;kc++) ah[kc] = *(const f16x8*)(hrow + kc*32 + l4*8);
  }

  f32x4 qacc[16];
  for (int ot=0;ot<16;ot++){
    size_t wrow = (size_t)(ot*16 + l15)*256 + l4*8;
    f32x4 a = (f32x4){0.f,0.f,0.f,0.f};
    #pragma unroll
    for (int kc=0;kc<8;kc++){
      f16x8 bh = *(const f16x8*)(Wqh + wrow + kc*32);
      f16x8 bl = *(const f16x8*)(Wql + wrow + kc*32);
      a = __builtin_amdgcn_mfma_f32_16x16x32_f16(ah[kc], bh, a, 0,0,0);
      a = __builtin_amdgcn_mfma_f32_16x16x32_f16(ah[kc], bl, a, 0,0,0);
    }
    qacc[ot] = a;
  }
  #pragma unroll
  for (int ot=0;ot<16;ot++){
    float bqv = bq[ot*16 + l15];
    #pragma unroll
    for (int r=0;r<4;r++) qacc[ot][r] += bqv;
  }

  // ---- transit Q hi/lo through Kb[1] (one-time; done before Kb[1] is prefetched) ----
  #pragma unroll
  for (int ot=0;ot<16;ot++){
    int o = ot*16 + l15;
    #pragma unroll
    for (int r=0;r<4;r++)
      Kb[1][(mb + l4*4 + r)*256 + o] = (_Float16)qacc[ot][r];
  }
  __syncthreads();
  f16x8 aqh[8];
  #pragma unroll
  for (int kc=0;kc<8;kc++) aqh[kc] = *(f16x8*)&Kb[1][(mb + l15)*256 + kc*32 + l4*8];
  __syncthreads();
  #pragma unroll
  for (int ot=0;ot<16;ot++){
    int o = ot*16 + l15;
    #pragma unroll
    for (int r=0;r<4;r++){
      float v = qacc[ot][r];
      _Float16 h = (_Float16)v;
      Kb[1][(mb + l4*4 + r)*256 + o] = (_Float16)(v - (float)h);
    }
  }
  __syncthreads();
  f16x8 aql[8];
  #pragma unroll
  for (int kc=0;kc<8;kc++) aql[kc] = *(f16x8*)&Kb[1][(mb + l15)*256 + kc*32 + l4*8];
  __syncthreads();                       // Kb[1] free for prefetch from here on

  f32x4 oacc[4][4];                      // [m-tile][d-tile], d-split: this wave owns dq..dq+63
  #pragma unroll
  for (int mt=0;mt<4;mt++)
    #pragma unroll
    for (int dt=0;dt<4;dt++) oacc[mt][dt] = (f32x4){0.f,0.f,0.f,0.f};
  float mrun[4], lrun[4];
  #pragma unroll
  for (int r=0;r<4;r++){ mrun[r] = -3.0e38f; lrun[r] = 0.f; }
  int dq = wave << 6;
  int sw = l15 & 7;

  #pragma unroll 2
  for (int c = 0; c < 16; ++c){
    int cur = c & 1;
    int s0 = c << 6;
    // prefetch next K chunk into the other buffer; drains at loop-end barrier
    if (c < 15) stage_k(Ehb, &Kb[cur^1][0], s0 + 64, wave, lane);

    // ---- QK^T (reads swizzled Kb[cur]) ----
    f32x4 sacc[4];
    #pragma unroll
    for (int st=0;st<4;st++){
      const _Float16* kb = &Kb[cur][(st*16 + l15)*256];
      f32x4 a = (f32x4){0.f,0.f,0.f,0.f};
      #pragma unroll
      for (int kc=0;kc<8;kc++){
        f16x8 bh = *(const f16x8*)(kb + (((kc*4 + l4) ^ sw) << 3));
        a = __builtin_amdgcn_mfma_f32_16x16x32_f16(aqh[kc], bh, a, 0,0,0);
        a = __builtin_amdgcn_mfma_f32_16x16x32_f16(aql[kc], bh, a, 0,0,0);
      }
      sacc[st] = a;
    }

    // ---- V fragments for this wave's d-quarter, direct from global (L2) ----
    f16x8 vv[2][4];
    #pragma unroll
    for (int kp=0;kp<2;kp++)
      #pragma unroll
      for (int dt=0;dt<4;dt++)
        vv[kp][dt] = *(const f16x8*)(EVb + (size_t)(dq + dt*16 + l15)*TE + s0 + kp*32 + l4*8);

    // ---- online softmax (owner wave: rows mb..mb+15) ----
    float alpha[4];
    #pragma unroll
    for (int r=0;r<4;r++){
      float cm = fmaxf(fmaxf(sacc[0][r], sacc[1][r]), fmaxf(sacc[2][r], sacc[3][r]));
      cm = fmaxf(cm, __shfl_xor(cm, 1));
      cm = fmaxf(cm, __shfl_xor(cm, 2));
      cm = fmaxf(cm, __shfl_xor(cm, 4));
      cm = fmaxf(cm, __shfl_xor(cm, 8));
      float mnew = fmaxf(mrun[r], cm);
      alpha[r] = __expf(mrun[r] - mnew);
      mrun[r] = mnew;
      float ps = 0.f;
      #pragma unroll
      for (int st=0;st<4;st++){
        float p = __expf(sacc[st][r] - mnew);
        sacc[st][r] = p;
        ps += p;
      }
      ps += __shfl_xor(ps, 1);
      ps += __shfl_xor(ps, 2);
      ps += __shfl_xor(ps, 4);
      ps += __shfl_xor(ps, 8);
      lrun[r] = lrun[r]*alpha[r] + ps;
    }

    // ---- publish P and alpha ----
    #pragma unroll
    for (int st=0;st<4;st++)
      #pragma unroll
      for (int r=0;r<4;r++)
        pb[mb + l4*4 + r][st*16 + l15] = (_Float16)sacc[st][r];
    if (l15 == 0){
      #pragma unroll
      for (int r=0;r<4;r++) alphas[mb + l4*4 + r] = alpha[r];
    }
    // raw barrier: wait LDS writes only — K prefetch stays in flight (no vmcnt drain)
    asm volatile("s_waitcnt lgkmcnt(0)" ::: "memory");
    __builtin_amdgcn_s_barrier();

    // ---- rescale + PV (d-split: all 64 rows, this wave's 64 d-columns) ----
    #pragma unroll
    for (int mt=0;mt<4;mt++){
      #pragma unroll
      for (int r=0;r<4;r++){
        float av = alphas[mt*16 + l4*4 + r];
        #pragma unroll
        for (int dt=0;dt<4;dt++) oacc[mt][dt][r] *= av;
      }
    }
    #pragma unroll
    for (int kp=0;kp<2;kp++){
      f16x8 pa[4];
      #pragma unroll
      for (int mt=0;mt<4;mt++) pa[mt] = *(f16x8*)&pb[mt*16 + l15][kp*32 + l4*8];
      #pragma unroll
      for (int dt=0;dt<4;dt++){
        #pragma unroll
        for (int mt=0;mt<4;mt++)
          oacc[mt][dt] = __builtin_amdgcn_mfma_f32_16x16x32_f16(pa[mt], vv[kp][dt], oacc[mt][dt], 0,0,0);
      }
    }
    __syncthreads();   // pbuf reads done + K prefetch drained (vmcnt 0) before next chunk
  }

  // ---- epilogue: publish 1/l, then H += O/l (fp16 RMW; each wave its d-quarter) ----
  if (l15 == 0){
    #pragma unroll
    for (int r=0;r<4;r++) linvs[mb + l4*4 + r] = 1.f / lrun[r];
  }
  __syncthreads();
  #pragma unroll
  for (int mt=0;mt<4;mt++){
    #pragma unroll
    for (int r=0;r<4;r++){
      float li = linvs[mt*16 + l4*4 + r];
      int t = t0 + mt*16 + l4*4 + r;
      _Float16* hp = &H[((size_t)b*TD + t)*DIM + dq];
      #pragma unroll
      for (int dt=0;dt<4;dt++){
        int idx = dt*16 + l15;
        hp[idx] = (_Float16)((float)hp[idx] + oacc[mt][dt][r] * li);
      }
    }
  }
}

// ---------- output projection as fp16 MFMA: out = Pb @ (Wph+Wpl)^T + bias ----------
__global__ __launch_bounds__(256) void k_proj_mfma(const _Float16* __restrict__ Hin,
    const _Float16* __restrict__ Wh, const _Float16* __restrict__ Wl,
    const float* __restrict__ bias, float* __restrict__ out)
{
  int blk = blockIdx.x;                 // 1024: 32 b x 32 t-tiles
  int b = blk >> 5;
  int t0 = (blk & 31) << 6;
  int tid = threadIdx.x;
  int wave = tid >> 6, lane = tid & 63;
  int l15 = lane & 15, l4 = lane >> 4;
  int mb = wave << 4;

  f16x8 ah[8];
  const _Float16* hrow = Hin + ((size_t)b*TD + t0 + mb + l15)*DIM;
  #pragma unroll
  for (int kc=0;kc<8;kc++) ah[kc] = *(const f16x8*)(hrow + kc*32 + l4*8);

  #pragma unroll
  for (int nt=0; nt<5; nt++){
    size_t wrow = (size_t)(nt*16 + l15)*256 + l4*8;
    f32x4 a = (f32x4){0.f,0.f,0.f,0.f};
    #pragma unroll
    for (int kc=0;kc<8;kc++){
      f16x8 bh = *(const f16x8*)(Wh + wrow + kc*32);
      f16x8 bl = *(const f16x8*)(Wl + wrow + kc*32);
      a = __builtin_amdgcn_mfma_f32_16x16x32_f16(ah[kc], bh, a, 0,0,0);
      a = __builtin_amdgcn_mfma_f32_16x16x32_f16(ah[kc], bl, a, 0,0,0);
    }
    int n = nt*16 + l15;
    float bv = bias[n];
    #pragma unroll
    for (int r=0;r<4;r++){
      int t = t0 + mb + l4*4 + r;
      out[((size_t)b*TD + t)*INDIM + n] = a[r] + bv;
    }
  }
}

extern "C" void kernel_launch(void* const* d_in, const int* in_sizes, int n_in,
                              void* d_out, int out_size, void* d_ws, size_t ws_size,
                              hipStream_t stream) {
  const float* enc   = (const float*)d_in[0];
  const float* emb   = (const float*)d_in[1];
  const float* mel   = (const float*)d_in[2];
  const float* W_lin = (const float*)d_in[3];
  const float* b_lin = (const float*)d_in[4];
  const float* w0    = (const float*)d_in[5];
  const float* b0    = (const float*)d_in[6];
  const float* w1    = (const float*)d_in[7];
  const float* b1    = (const float*)d_in[8];
  const float* Wq    = (const float*)d_in[9];
  const float* bq    = (const float*)d_in[10];
  const float* Wp    = (const float*)d_in[11];
  const float* bp    = (const float*)d_in[12];
  float* out = (float*)d_out;

  const size_t NTOK = (size_t)BB*TD*DIM;           // 16.78M
  const size_t NE   = (size_t)BB*TE*DIM;           // 8.39M
  _Float16* Xb  = (_Float16*)d_ws;
  _Float16* H   = Xb + NTOK;                       // fp16 end-to-end
  _Float16* Wf0 = H + NTOK;
  _Float16* Wf1 = Wf0 + (size_t)512*1280;
  _Float16* Wqh = Wf1 + (size_t)512*1280;
  _Float16* Wql = Wqh + 65536;
  _Float16* Wlh = Wql + 65536;                     // 256*96
  _Float16* Wll = Wlh + 24576;
  _Float16* Wph = Wll + 24576;                     // 80*256
  _Float16* Wpl = Wph + 20480;
  _Float16* Eh  = Xb;                              // after conv0 consumes Xb
  _Float16* EVt = Xb + NE;
  _Float16* Pb  = Xb;                              // after attn consumes Eh/EVt

  k_prep     <<<5552, 256, 0, stream>>>(w0, w1, Wq, W_lin, Wp,
                                        Wf0, Wf1, Wqh, Wql, Wlh, Wll, Wph, Wpl);
  k_lin_mfma <<<1024, 256, 0, stream>>>(mel, Wlh, Wll, b_lin, Xb);
  k_conv_mfma<<<2048, 256, 0, stream>>>(Xb, Wf0, b0, H);
  k_eprep    <<<2048, 256, 0, stream>>>(enc, emb, Eh, EVt);
  k_attn     <<<1024, 256, 0, stream>>>(H, Wqh, Wql, bq, Eh, EVt);
  k_conv_mfma<<<2048, 256, 0, stream>>>(H, Wf1, b1, Pb);
  k_proj_mfma<<<1024, 256, 0, stream>>>(Pb, Wph, Wpl, bp, out);
}

// Round 12
// 742.767 us; speedup vs baseline: 1.1483x; 1.0018x over previous
//
#include <hip/hip_runtime.h>
#include <math.h>

#define BB 32
#define TD 2048
#define TE 1024
#define DIM 256
#define INDIM 80

typedef __attribute__((ext_vector_type(8))) _Float16 f16x8;
typedef __attribute__((ext_vector_type(4))) float f32x4;

__device__ __forceinline__ float sigmoidf_(float x){ return 1.f/(1.f+__expf(-x)); }

// async 16B global->LDS copy (direct DMA, no VGPR round-trip)
__device__ __forceinline__ void cp16(const _Float16* g, _Float16* l){
  __builtin_amdgcn_global_load_lds(
      (const __attribute__((address_space(1))) unsigned int*)g,
      (__attribute__((address_space(3))) unsigned int*)l, 16, 0, 0);
}

// ------- merged weight prep: conv reorders + 2-term fp16 splits, one launch -------
// Conv sections are READ-coalesced (thread i = source-linear; writes scatter,
// but writes don't stall — the stride-20B read pattern was the 5x over-fetch).
__global__ __launch_bounds__(256) void k_prep(
    const float* __restrict__ w0, const float* __restrict__ w1,
    const float* __restrict__ Wq, const float* __restrict__ Wl,
    const float* __restrict__ Wp,
    _Float16* __restrict__ Wf0, _Float16* __restrict__ Wf1,
    _Float16* __restrict__ Wqh, _Float16* __restrict__ Wql,
    _Float16* __restrict__ Wlh, _Float16* __restrict__ Wll,
    _Float16* __restrict__ Wph, _Float16* __restrict__ Wpl)
{
  int i = blockIdx.x*256 + threadIdx.x;
  if (i < 655360){
    int o = i / 1280, rem = i - o*1280;
    int ic = rem / 5, tap = rem - ic*5;
    Wf0[o*1280 + tap*256 + ic] = (_Float16)w0[i];
  } else if (i < 1310720){
    int j = i - 655360;
    int o = j / 1280, rem = j - o*1280;
    int ic = rem / 5, tap = rem - ic*5;
    Wf1[o*1280 + tap*256 + ic] = (_Float16)w1[j];
  } else if (i < 1376256){
    int j = i - 1310720;
    float f = Wq[j];
    _Float16 h = (_Float16)f;
    Wqh[j] = h; Wql[j] = (_Float16)(f - (float)h);
  } else if (i < 1400832){
    int j = i - 1376256;
    int d = j / 96, k = j - d*96;
    float f = (k < INDIM) ? Wl[d*INDIM + k] : 0.f;
    _Float16 h = (_Float16)f;
    Wlh[j] = h; Wll[j] = (_Float16)(f - (float)h);
  } else {
    int j = i - 1400832;
    float f = Wp[j];
    _Float16 h = (_Float16)f;
    Wph[j] = h; Wpl[j] = (_Float16)(f - (float)h);
  }
}

// ------- enc prep: Eh = fp16(enc) [b][s][d];  EVt = fp16(enc+emb) transposed [b][d][s] ---
// Vectorized: float4-pair loads, f16x8 stores on both paths (was 2B scalar stores).
__global__ __launch_bounds__(256) void k_eprep(const float* __restrict__ enc,
    const float* __restrict__ emb, _Float16* __restrict__ Eh,
    _Float16* __restrict__ EVt)
{
  __shared__ float ls[64][65];
  int blk = blockIdx.x;                  // 32 b * 16 st * 4 dt = 2048
  int dt = blk & 3, st = (blk>>2) & 15, b = blk >> 6;
  int s0 = st*64, d0 = dt*64;
  int tid = threadIdx.x;
  #pragma unroll
  for (int k=0;k<2;k++){
    int slot = k*256 + tid;              // 512 slots: 64 rows x 8 col-groups
    int r = slot >> 3, cg = (slot & 7) << 3;
    size_t gi = ((size_t)b*TE + s0 + r)*DIM + d0 + cg;
    const float4* pe = (const float4*)(enc + gi);
    const float4* pm = (const float4*)(emb + gi);
    float4 e0 = pe[0], e1 = pe[1];
    float4 m0 = pm[0], m1 = pm[1];
    f16x8 v;
    v[0]=(_Float16)e0.x; v[1]=(_Float16)e0.y; v[2]=(_Float16)e0.z; v[3]=(_Float16)e0.w;
    v[4]=(_Float16)e1.x; v[5]=(_Float16)e1.y; v[6]=(_Float16)e1.z; v[7]=(_Float16)e1.w;
    *(f16x8*)&Eh[gi] = v;
    ls[r][cg+0]=e0.x+m0.x; ls[r][cg+1]=e0.y+m0.y; ls[r][cg+2]=e0.z+m0.z; ls[r][cg+3]=e0.w+m0.w;
    ls[r][cg+4]=e1.x+m1.x; ls[r][cg+5]=e1.y+m1.y; ls[r][cg+6]=e1.z+m1.z; ls[r][cg+7]=e1.w+m1.w;
  }
  __syncthreads();
  #pragma unroll
  for (int k=0;k<2;k++){
    int slot = k*256 + tid;
    int r = slot >> 3, cg = (slot & 7) << 3;   // r = d index, cg = s offset
    f16x8 v;
    #pragma unroll
    for (int j=0;j<8;j++) v[j] = (_Float16)ls[cg+j][r];
    *(f16x8*)&EVt[((size_t)b*DIM + d0 + r)*TE + s0 + cg] = v;
  }
}

// ---------- input linear + shift-right as fp16 MFMA: X = shift(mel) @ W_lin^T ----------
__global__ __launch_bounds__(256) void k_lin_mfma(const float* __restrict__ mel,
    const _Float16* __restrict__ Wh, const _Float16* __restrict__ Wl,
    const float* __restrict__ bias, _Float16* __restrict__ X)
{
  __shared__ __align__(16) _Float16 ms[64*104];   // 64 rows x 96 cols (pad 104)
  int blk = blockIdx.x;                 // 1024: 32 b x 32 t-tiles
  int b = blk >> 5;
  int t0 = (blk & 31) << 6;
  int tid = threadIdx.x;

  for (int i = tid; i < 64*12; i += 256){
    int row = i / 12, cg = (i - row*12) * 8;
    int t = t0 + row - 1;               // shifted: X[t] = lin(mel[t-1])
    f16x8 v = {};
    if (t >= 0 && cg < INDIM){
      const float4* p = (const float4*)(mel + ((size_t)b*TD + t)*INDIM + cg);
      float4 f0 = p[0], f1 = p[1];
      v[0]=(_Float16)f0.x; v[1]=(_Float16)f0.y; v[2]=(_Float16)f0.z; v[3]=(_Float16)f0.w;
      v[4]=(_Float16)f1.x; v[5]=(_Float16)f1.y; v[6]=(_Float16)f1.z; v[7]=(_Float16)f1.w;
    }
    *(f16x8*)&ms[row*104 + cg] = v;
  }
  __syncthreads();

  int wave = tid >> 6, lane = tid & 63;
  int l15 = lane & 15, l4 = lane >> 4;
  int mb = wave << 4;

  f16x8 am[3];
  #pragma unroll
  for (int kc=0;kc<3;kc++) am[kc] = *(f16x8*)&ms[(mb + l15)*104 + kc*32 + l4*8];

  for (int dt=0; dt<16; dt++){
    size_t wrow = (size_t)(dt*16 + l15)*96 + l4*8;
    f32x4 a = (f32x4){0.f,0.f,0.f,0.f};
    #pragma unroll
    for (int kc=0;kc<3;kc++){
      f16x8 bh = *(const f16x8*)(Wh + wrow + kc*32);
      f16x8 bl = *(const f16x8*)(Wl + wrow + kc*32);
      a = __builtin_amdgcn_mfma_f32_16x16x32_f16(am[kc], bh, a, 0,0,0);
      a = __builtin_amdgcn_mfma_f32_16x16x32_f16(am[kc], bl, a, 0,0,0);
    }
    int d = dt*16 + l15;
    float bv = bias[d];
    #pragma unroll
    for (int r=0;r<4;r++){
      int m = mb + l4*4 + r;
      int t = t0 + m;
      X[((size_t)b*TD + t)*DIM + d] = (t==0) ? (_Float16)0.f : (_Float16)(a[r] + bv);
    }
  }
}

// ------- conv-GLU as fp16 MFMA GEMM (128t x 64d per block, weight prefetch 2) -------
__global__ __launch_bounds__(256) void k_conv_mfma(const _Float16* __restrict__ Xin,
    const _Float16* __restrict__ Wf, const float* __restrict__ bias,
    _Float16* __restrict__ Hout)
{
  __shared__ __align__(16) _Float16 as[132*264];  // 69.7 KB
  int id = blockIdx.x;                 // 2048: 32b x 16 mtile x 4 dtile
  int dtile = id & 3;
  int mtile = (id >> 2) & 15;
  int b = id >> 6;
  int t0 = mtile << 7;
  int d0 = dtile << 6;
  int tid = threadIdx.x;

  for (int i = tid; i < 132*32; i += 256){
    int row = i >> 5, cg = (i & 31) << 3;
    int t = t0 - 4 + row;
    f16x8 v = {};
    if (t >= 0)
      v = *(const f16x8*)(Xin + ((size_t)b*TD + t)*DIM + cg);
    *(f16x8*)&as[row*264 + cg] = v;
  }
  __syncthreads();

  int lane = tid & 63, wave = tid >> 6;
  int l15 = lane & 15, l4 = lane >> 4;
  int dA = d0 + (wave << 4) + l15;

  const _Float16* pA = Wf + (size_t)dA*1280 + l4*8;
  const _Float16* pG = Wf + (size_t)(256 + dA)*1280 + l4*8;

  f32x4 aca[8], acg[8];
  #pragma unroll
  for (int mt=0;mt<8;mt++){ aca[mt]=(f32x4){0.f,0.f,0.f,0.f}; acg[mt]=(f32x4){0.f,0.f,0.f,0.f}; }

  // weight stream, 2-deep prefetch
  f16x8 a0 = *(const f16x8*)pA;
  f16x8 g0 = *(const f16x8*)pG;
  f16x8 a1 = *(const f16x8*)(pA + 32);
  f16x8 g1 = *(const f16x8*)(pG + 32);
  #pragma unroll
  for (int kc = 0; kc < 40; ++kc){
    f16x8 a2 = a1, g2 = g1;
    if (kc < 38){
      a2 = *(const f16x8*)(pA + (kc+2)*32);
      g2 = *(const f16x8*)(pG + (kc+2)*32);
    }
    int tap = kc >> 3;
    int ic0 = (kc & 7) << 5;
    int abase = (l15 + tap)*264 + ic0 + l4*8;
    #pragma unroll
    for (int mt=0;mt<8;mt++){
      f16x8 av = *(f16x8*)&as[abase + mt*16*264];
      aca[mt] = __builtin_amdgcn_mfma_f32_16x16x32_f16(av, a0, aca[mt], 0,0,0);
      acg[mt] = __builtin_amdgcn_mfma_f32_16x16x32_f16(av, g0, acg[mt], 0,0,0);
    }
    a0 = a1; g0 = g1; a1 = a2; g1 = g2;
  }

  const float is2 = 0.7071067811865476f;
  float ba = bias[dA], bg = bias[256 + dA];
  #pragma unroll
  for (int mt=0; mt<8; mt++){
    #pragma unroll
    for (int r=0;r<4;r++){
      int m = mt*16 + l4*4 + r;
      size_t orow = ((size_t)b*TD + t0 + m)*DIM;
      float xr = (float)as[(m+4)*264 + dA];
      float a = aca[mt][r] + ba;
      float g = acg[mt][r] + bg;
      Hout[orow + dA] = (_Float16)((a*sigmoidf_(g) + xr)*is2);
    }
  }
}

// ---------- fused q-linear + flash attention + residual ----------
// R8/R10/R11 banked-best structure, byte-for-byte. H fp16 end-to-end. FROZEN.
__device__ __forceinline__ void stage_k(const _Float16* __restrict__ Ehb,
    _Float16* __restrict__ dst, int srow0, int wave, int lane)
{
  int r2 = lane >> 5, cu = lane & 31;
  #pragma unroll
  for (int ii=0; ii<8; ii++){
    int row = (ii*4 + wave)*2 + r2;                       // 0..63
    cp16(Ehb + (size_t)(srow0 + row)*DIM + ((cu ^ (row & 7)) << 3),
         dst + (ii*4 + wave)*512);                        // wave-uniform LDS base
  }
}

__global__ __launch_bounds__(256) void k_attn(_Float16* __restrict__ H,
    const _Float16* __restrict__ Wqh, const _Float16* __restrict__ Wql,
    const float* __restrict__ bq,
    const _Float16* __restrict__ Eh, const _Float16* __restrict__ EVt)
{
  __shared__ __align__(16) _Float16 Kb[2][64*256];   // 64 KB K double-buffer (swizzled)
  __shared__ __align__(16) _Float16 pb[64][72];      // 9.2 KB P chunk (cross-wave)
  __shared__ float alphas[64];
  __shared__ float linvs[64];

  int i = blockIdx.x;                   // XCD swizzle: same-batch blocks share an XCD
  int b = (i & 7) | ((i >> 8) << 3);
  int t0 = ((i >> 3) & 31) << 6;
  int tid = threadIdx.x;
  int wave = tid >> 6, lane = tid & 63;
  int l15 = lane & 15, l4 = lane >> 4;
  int mb = wave << 4;

  const _Float16* Ehb = Eh + (size_t)b*TE*DIM;
  const _Float16* EVb = EVt + (size_t)b*DIM*TE;

  // prefetch K chunk 0 into Kb[0] (latency hidden under the whole q-linear)
  stage_k(Ehb, &Kb[0][0], 0, wave, lane);

  // ---- q-linear (2-term fp16); H is fp16 -> direct fragment loads ----
  f16x8 ah[8];
  {
    const _Float16* hrow = H + ((size_t)b*TD + t0 + mb + l15)*DIM;
    #pragma unroll
    for (int kc=0;kc<8;kc++) ah[kc] = *(const f16x8*)(hrow + kc*32 + l4*8);
  }

  f32x4 qacc[16];
  for (int ot=0;ot<16;ot++){
    size_t wrow = (size_t)(ot*16 + l15)*256 + l4*8;
    f32x4 a = (f32x4){0.f,0.f,0.f,0.f};
    #pragma unroll
    for (int kc=0;kc<8;kc++){
      f16x8 bh = *(const f16x8*)(Wqh + wrow + kc*32);
      f16x8 bl = *(const f16x8*)(Wql + wrow + kc*32);
      a = __builtin_amdgcn_mfma_f32_16x16x32_f16(ah[kc], bh, a, 0,0,0);
      a = __builtin_amdgcn_mfma_f32_16x16x32_f16(ah[kc], bl, a, 0,0,0);
    }
    qacc[ot] = a;
  }
  #pragma unroll
  for (int ot=0;ot<16;ot++){
    float bqv = bq[ot*16 + l15];
    #pragma unroll
    for (int r=0;r<4;r++) qacc[ot][r] += bqv;
  }

  // ---- transit Q hi/lo through Kb[1] (one-time; done before Kb[1] is prefetched) ----
  #pragma unroll
  for (int ot=0;ot<16;ot++){
    int o = ot*16 + l15;
    #pragma unroll
    for (int r=0;r<4;r++)
      Kb[1][(mb + l4*4 + r)*256 + o] = (_Float16)qacc[ot][r];
  }
  __syncthreads();
  f16x8 aqh[8];
  #pragma unroll
  for (int kc=0;kc<8;kc++) aqh[kc] = *(f16x8*)&Kb[1][(mb + l15)*256 + kc*32 + l4*8];
  __syncthreads();
  #pragma unroll
  for (int ot=0;ot<16;ot++){
    int o = ot*16 + l15;
    #pragma unroll
    for (int r=0;r<4;r++){
      float v = qacc[ot][r];
      _Float16 h = (_Float16)v;
      Kb[1][(mb + l4*4 + r)*256 + o] = (_Float16)(v - (float)h);
    }
  }
  __syncthreads();
  f16x8 aql[8];
  #pragma unroll
  for (int kc=0;kc<8;kc++) aql[kc] = *(f16x8*)&Kb[1][(mb + l15)*256 + kc*32 + l4*8];
  __syncthreads();                       // Kb[1] free for prefetch from here on

  f32x4 oacc[4][4];                      // [m-tile][d-tile], d-split: this wave owns dq..dq+63
  #pragma unroll
  for (int mt=0;mt<4;mt++)
    #pragma unroll
    for (int dt=0;dt<4;dt++) oacc[mt][dt] = (f32x4){0.f,0.f,0.f,0.f};
  float mrun[4], lrun[4];
  #pragma unroll
  for (int r=0;r<4;r++){ mrun[r] = -3.0e38f; lrun[r] = 0.f; }
  int dq = wave << 6;
  int sw = l15 & 7;

  #pragma unroll 2
  for (int c = 0; c < 16; ++c){
    int cur = c & 1;
    int s0 = c << 6;
    // prefetch next K chunk into the other buffer; drains at loop-end barrier
    if (c < 15) stage_k(Ehb, &Kb[cur^1][0], s0 + 64, wave, lane);

    // ---- QK^T (reads swizzled Kb[cur]) ----
    f32x4 sacc[4];
    #pragma unroll
    for (int st=0;st<4;st++){
      const _Float16* kb = &Kb[cur][(st*16 + l15)*256];
      f32x4 a = (f32x4){0.f,0.f,0.f,0.f};
      #pragma unroll
      for (int kc=0;kc<8;kc++){
        f16x8 bh = *(const f16x8*)(kb + (((kc*4 + l4) ^ sw) << 3));
        a = __builtin_amdgcn_mfma_f32_16x16x32_f16(aqh[kc], bh, a, 0,0,0);
        a = __builtin_amdgcn_mfma_f32_16x16x32_f16(aql[kc], bh, a, 0,0,0);
      }
      sacc[st] = a;
    }

    // ---- V fragments for this wave's d-quarter, direct from global (L2) ----
    f16x8 vv[2][4];
    #pragma unroll
    for (int kp=0;kp<2;kp++)
      #pragma unroll
      for (int dt=0;dt<4;dt++)
        vv[kp][dt] = *(const f16x8*)(EVb + (size_t)(dq + dt*16 + l15)*TE + s0 + kp*32 + l4*8);

    // ---- online softmax (owner wave: rows mb..mb+15) ----
    float alpha[4];
    #pragma unroll
    for (int r=0;r<4;r++){
      float cm = fmaxf(fmaxf(sacc[0][r], sacc[1][r]), fmaxf(sacc[2][r], sacc[3][r]));
      cm = fmaxf(cm, __shfl_xor(cm, 1));
      cm = fmaxf(cm, __shfl_xor(cm, 2));
      cm = fmaxf(cm, __shfl_xor(cm, 4));
      cm = fmaxf(cm, __shfl_xor(cm, 8));
      float mnew = fmaxf(mrun[r], cm);
      alpha[r] = __expf(mrun[r] - mnew);
      mrun[r] = mnew;
      float ps = 0.f;
      #pragma unroll
      for (int st=0;st<4;st++){
        float p = __expf(sacc[st][r] - mnew);
        sacc[st][r] = p;
        ps += p;
      }
      ps += __shfl_xor(ps, 1);
      ps += __shfl_xor(ps, 2);
      ps += __shfl_xor(ps, 4);
      ps += __shfl_xor(ps, 8);
      lrun[r] = lrun[r]*alpha[r] + ps;
    }

    // ---- publish P and alpha ----
    #pragma unroll
    for (int st=0;st<4;st++)
      #pragma unroll
      for (int r=0;r<4;r++)
        pb[mb + l4*4 + r][st*16 + l15] = (_Float16)sacc[st][r];
    if (l15 == 0){
      #pragma unroll
      for (int r=0;r<4;r++) alphas[mb + l4*4 + r] = alpha[r];
    }
    // raw barrier: wait LDS writes only — K prefetch stays in flight (no vmcnt drain)
    asm volatile("s_waitcnt lgkmcnt(0)" ::: "memory");
    __builtin_amdgcn_s_barrier();

    // ---- rescale + PV (d-split: all 64 rows, this wave's 64 d-columns) ----
    #pragma unroll
    for (int mt=0;mt<4;mt++){
      #pragma unroll
      for (int r=0;r<4;r++){
        float av = alphas[mt*16 + l4*4 + r];
        #pragma unroll
        for (int dt=0;dt<4;dt++) oacc[mt][dt][r] *= av;
      }
    }
    #pragma unroll
    for (int kp=0;kp<2;kp++){
      f16x8 pa[4];
      #pragma unroll
      for (int mt=0;mt<4;mt++) pa[mt] = *(f16x8*)&pb[mt*16 + l15][kp*32 + l4*8];
      #pragma unroll
      for (int dt=0;dt<4;dt++){
        #pragma unroll
        for (int mt=0;mt<4;mt++)
          oacc[mt][dt] = __builtin_amdgcn_mfma_f32_16x16x32_f16(pa[mt], vv[kp][dt], oacc[mt][dt], 0,0,0);
      }
    }
    __syncthreads();   // pbuf reads done + K prefetch drained (vmcnt 0) before next chunk
  }

  // ---- epilogue: publish 1/l, then H += O/l (fp16 RMW; each wave its d-quarter) ----
  if (l15 == 0){
    #pragma unroll
    for (int r=0;r<4;r++) linvs[mb + l4*4 + r] = 1.f / lrun[r];
  }
  __syncthreads();
  #pragma unroll
  for (int mt=0;mt<4;mt++){
    #pragma unroll
    for (int r=0;r<4;r++){
      float li = linvs[mt*16 + l4*4 + r];
      int t = t0 + mt*16 + l4*4 + r;
      _Float16* hp = &H[((size_t)b*TD + t)*DIM + dq];
      #pragma unroll
      for (int dt=0;dt<4;dt++){
        int idx = dt*16 + l15;
        hp[idx] = (_Float16)((float)hp[idx] + oacc[mt][dt][r] * li);
      }
    }
  }
}

// ---------- output projection as fp16 MFMA: out = Pb @ (Wph+Wpl)^T + bias ----------
__global__ __launch_bounds__(256) void k_proj_mfma(const _Float16* __restrict__ Hin,
    const _Float16* __restrict__ Wh, const _Float16* __restrict__ Wl,
    const float* __restrict__ bias, float* __restrict__ out)
{
  int blk = blockIdx.x;                 // 1024: 32 b x 32 t-tiles
  int b = blk >> 5;
  int t0 = (blk & 31) << 6;
  int tid = threadIdx.x;
  int wave = tid >> 6, lane = tid & 63;
  int l15 = lane & 15, l4 = lane >> 4;
  int mb = wave << 4;

  f16x8 ah[8];
  const _Float16* hrow = Hin + ((size_t)b*TD + t0 + mb + l15)*DIM;
  #pragma unroll
  for (int kc=0;kc<8;kc++) ah[kc] = *(const f16x8*)(hrow + kc*32 + l4*8);

  #pragma unroll
  for (int nt=0; nt<5; nt++){
    size_t wrow = (size_t)(nt*16 + l15)*256 + l4*8;
    f32x4 a = (f32x4){0.f,0.f,0.f,0.f};
    #pragma unroll
    for (int kc=0;kc<8;kc++){
      f16x8 bh = *(const f16x8*)(Wh + wrow + kc*32);
      f16x8 bl = *(const f16x8*)(Wl + wrow + kc*32);
      a = __builtin_amdgcn_mfma_f32_16x16x32_f16(ah[kc], bh, a, 0,0,0);
      a = __builtin_amdgcn_mfma_f32_16x16x32_f16(ah[kc], bl, a, 0,0,0);
    }
    int n = nt*16 + l15;
    float bv = bias[n];
    #pragma unroll
    for (int r=0;r<4;r++){
      int t = t0 + mb + l4*4 + r;
      out[((size_t)b*TD + t)*INDIM + n] = a[r] + bv;
    }
  }
}

extern "C" void kernel_launch(void* const* d_in, const int* in_sizes, int n_in,
                              void* d_out, int out_size, void* d_ws, size_t ws_size,
                              hipStream_t stream) {
  const float* enc   = (const float*)d_in[0];
  const float* emb   = (const float*)d_in[1];
  const float* mel   = (const float*)d_in[2];
  const float* W_lin = (const float*)d_in[3];
  const float* b_lin = (const float*)d_in[4];
  const float* w0    = (const float*)d_in[5];
  const float* b0    = (const float*)d_in[6];
  const float* w1    = (const float*)d_in[7];
  const float* b1    = (const float*)d_in[8];
  const float* Wq    = (const float*)d_in[9];
  const float* bq    = (const float*)d_in[10];
  const float* Wp    = (const float*)d_in[11];
  const float* bp    = (const float*)d_in[12];
  float* out = (float*)d_out;

  const size_t NTOK = (size_t)BB*TD*DIM;           // 16.78M
  const size_t NE   = (size_t)BB*TE*DIM;           // 8.39M
  _Float16* Xb  = (_Float16*)d_ws;
  _Float16* H   = Xb + NTOK;                       // fp16 end-to-end
  _Float16* Wf0 = H + NTOK;
  _Float16* Wf1 = Wf0 + (size_t)512*1280;
  _Float16* Wqh = Wf1 + (size_t)512*1280;
  _Float16* Wql = Wqh + 65536;
  _Float16* Wlh = Wql + 65536;                     // 256*96
  _Float16* Wll = Wlh + 24576;
  _Float16* Wph = Wll + 24576;                     // 80*256
  _Float16* Wpl = Wph + 20480;
  _Float16* Eh  = Xb;                              // after conv0 consumes Xb
  _Float16* EVt = Xb + NE;
  _Float16* Pb  = Xb;                              // after attn consumes Eh/EVt

  k_prep     <<<5552, 256, 0, stream>>>(w0, w1, Wq, W_lin, Wp,
                                        Wf0, Wf1, Wqh, Wql, Wlh, Wll, Wph, Wpl);
  k_lin_mfma <<<1024, 256, 0, stream>>>(mel, Wlh, Wll, b_lin, Xb);
  k_conv_mfma<<<2048, 256, 0, stream>>>(Xb, Wf0, b0, H);
  k_eprep    <<<2048, 256, 0, stream>>>(enc, emb, Eh, EVt);
  k_attn     <<<1024, 256, 0, stream>>>(H, Wqh, Wql, bq, Eh, EVt);
  k_conv_mfma<<<2048, 256, 0, stream>>>(H, Wf1, b1, Pb);
  k_proj_mfma<<<1024, 256, 0, stream>>>(Pb, Wph, Wpl, bp, out);
}